// Round 4
// baseline (1546.882 us; speedup 1.0000x reference)
//
#include <hip/hip_runtime.h>

constexpr int NC = 100000;
constexpr int NQ = 20000;
constexpr int FC = 300;
constexpr int FQ = 768;
constexpr int NEDGE = 400000;
constexpr int NTOT = NC + NC + NQ;  // concatenated dst segments: et0 | et1 | et2
constexpr float SCALE = 0.17677669529663687f;  // 1/sqrt(32)

typedef __attribute__((ext_vector_type(8))) short bf16x8;
typedef __attribute__((ext_vector_type(4))) float f32x4;
typedef unsigned short u16;

struct PDst {
  void* p[5];
  int ld[5];
  int cb[5];
  int isbf[5];
};

__device__ __forceinline__ float gelu_f(float x) {
  return 0.5f * x * (1.0f + erff(x * 0.7071067811865476f));
}
__device__ __forceinline__ u16 bf16_rne(float x) {
  unsigned u = __float_as_uint(x);
  unsigned r = u + 0x7fffu + ((u >> 16) & 1u);
  return (u16)(r >> 16);
}
__device__ __forceinline__ float bf16_to_f(u16 h) {
  return __uint_as_float(((unsigned)h) << 16);
}
__device__ __forceinline__ void split2(float x, u16& hi, u16& lo) {
  hi = bf16_rne(x);
  lo = bf16_rne(x - bf16_to_f(hi));
}

// ---------------- fused CSR build over 3 edge types ----------------
__global__ void k_count3(const int* __restrict__ d0, const int* __restrict__ d1,
                         const int* __restrict__ d2, int* __restrict__ counts) {
  int i = blockIdx.x * 256 + threadIdx.x;
  if (i >= 3 * NEDGE) return;
  int et = i / NEDGE, e = i - et * NEDGE;
  int d = (et == 0) ? d0[e] : (et == 1) ? d1[e] : d2[e];
  int base = (et == 0) ? 0 : (et == 1) ? NC : 2 * NC;
  atomicAdd(&counts[base + d], 1);
}

__global__ void k_scan_block(const int* __restrict__ in, int* __restrict__ out,
                             int* __restrict__ bsum, int n) {
  __shared__ int s[256];
  int tid = threadIdx.x;
  int i = blockIdx.x * 256 + tid;
  int v = (i < n) ? in[i] : 0;
  s[tid] = v;
  __syncthreads();
  for (int off = 1; off < 256; off <<= 1) {
    int t = (tid >= off) ? s[tid - off] : 0;
    __syncthreads();
    s[tid] += t;
    __syncthreads();
  }
  if (i < n) out[i] = s[tid] - v;
  if (tid == 255) bsum[blockIdx.x] = s[255];
}

__global__ void k_scan_sums(int* __restrict__ bsum, int nb) {
  __shared__ int s[1024];
  int tid = threadIdx.x;
  int v = (tid < nb) ? bsum[tid] : 0;
  s[tid] = v;
  __syncthreads();
  for (int off = 1; off < 1024; off <<= 1) {
    int t = (tid >= off) ? s[tid - off] : 0;
    __syncthreads();
    s[tid] += t;
    __syncthreads();
  }
  if (tid < nb) bsum[tid] = s[tid] - v;
}

__global__ void k_scan_add(int* __restrict__ ptr, const int* __restrict__ bsum, int n, int total) {
  int i = blockIdx.x * 256 + threadIdx.x;
  if (i < n) ptr[i] += bsum[blockIdx.x];
  if (i == 0) ptr[n] = total;
}

__global__ void k_copy(int* __restrict__ dst, const int* __restrict__ src, int n) {
  int i = blockIdx.x * 256 + threadIdx.x;
  if (i < n) dst[i] = src[i];
}

__global__ void k_scatter3(const int* __restrict__ s0, const int* __restrict__ s1,
                           const int* __restrict__ s2, const int* __restrict__ d0,
                           const int* __restrict__ d1, const int* __restrict__ d2,
                           int* __restrict__ cursor, int* __restrict__ srcs_out) {
  int i = blockIdx.x * 256 + threadIdx.x;
  if (i >= 3 * NEDGE) return;
  int et = i / NEDGE, e = i - et * NEDGE;
  int d = (et == 0) ? d0[e] : (et == 1) ? d1[e] : d2[e];
  int sv = (et == 0) ? s0[e] : (et == 1) ? s1[e] : s2[e];
  int base = (et == 0) ? 0 : (et == 1) ? NC : 2 * NC;
  int p = atomicAdd(&cursor[base + d], 1);
  srcs_out[p] = sv;
}

// ---------------- per-layer B preparation: q split + 2 or 4 rel-folds ----------------
// blockIdx.y==0: plain transpose+split of Wq (K=N=128).
// y>=1: fold W{k,v} with rel, colOff = y*128.  y odd->k (relA, prel, SCALE), y even->v (relM).
__global__ void prep_B(const float* __restrict__ Wq, const float* __restrict__ bq,
                       const float* __restrict__ Wk, const float* __restrict__ bk,
                       const float* __restrict__ Wv, const float* __restrict__ bv,
                       const float* __restrict__ relA0, const float* __restrict__ relM0,
                       const float* __restrict__ prel0,
                       const float* __restrict__ relA1, const float* __restrict__ relM1,
                       const float* __restrict__ prel1,
                       u16* __restrict__ Bth, u16* __restrict__ Btl,
                       float* __restrict__ biasOut) {
  int i = blockIdx.x;     // input dim (k) 0..127
  int col = threadIdx.x;  // output col 0..127
  int y = blockIdx.y;
  if (y == 0) {
    float v = Wq[i * 128 + col];
    u16 hi, lo;
    split2(v, hi, lo);
    Bth[(size_t)col * 128 + i] = hi;
    Btl[(size_t)col * 128 + i] = lo;
    if (i == 0) biasOut[col] = bq[col];
    return;
  }
  int pair = (y - 1) >> 1;             // 0: first et, 1: second et
  bool isK = ((y - 1) & 1) == 0;       // y=1,3 -> k ; y=2,4 -> v
  const float* W = isK ? Wk : Wv;
  const float* bb = isK ? bk : bv;
  const float* rel = isK ? (pair ? relA1 : relA0) : (pair ? relM1 : relM0);
  const float* pr = isK ? (pair ? prel1 : prel0) : nullptr;
  int h = col >> 5, f = col & 31;
  float m = (pr ? pr[h] : 1.0f) * (isK ? SCALE : 1.0f);
  float s = 0.0f;
  #pragma unroll
  for (int d = 0; d < 32; ++d)
    s += W[i * 128 + h * 32 + d] * rel[(h * 32 + d) * 32 + f];
  s *= m;
  u16 hi, lo;
  split2(s, hi, lo);
  int colOff = y * 128;
  Bth[(size_t)(colOff + col) * 128 + i] = hi;
  Btl[(size_t)(colOff + col) * 128 + i] = lo;
  if (i == 0) {
    float sb = 0.0f;
    #pragma unroll
    for (int d = 0; d < 32; ++d)
      sb += bb[h * 32 + d] * rel[(h * 32 + d) * 32 + f];
    biasOut[colOff + col] = sb * m;
  }
}

// ---------------- split+transpose plain weight W[KxN(=128)] -> Bt[N x Kp] ----------------
__global__ void split_w(const float* __restrict__ W, const float* __restrict__ b,
                        u16* __restrict__ Bth, u16* __restrict__ Btl,
                        float* __restrict__ biasOut, int K, int Kp) {
  int n = blockIdx.x;
  for (int k = threadIdx.x; k < Kp; k += blockDim.x) {
    float v = (k < K) ? W[(size_t)k * 128 + n] : 0.0f;
    u16 hi, lo;
    split2(v, hi, lo);
    Bth[(size_t)n * Kp + k] = hi;
    Btl[(size_t)n * Kp + k] = lo;
  }
  if (threadIdx.x == 0) biasOut[n] = b[n];
}

// ---------------- K=128 projection GEMM: A staged once in LDS, loop over N-slabs ----------------
// A pre-split [M x 128] hi/lo; B pre-split transposed [NSLAB*128 x 128]; B read from global (L2).
template <int NSLAB>
__global__ __launch_bounds__(256) void proj_gemm(
    const u16* __restrict__ Ahg, const u16* __restrict__ Alg,
    const u16* __restrict__ Bth, const u16* __restrict__ Btl,
    const float* __restrict__ bias, PDst dst, int M) {
  __shared__ u16 Ah[4][128][40];
  __shared__ u16 Al[4][128][40];
  const int tid = threadIdx.x;
  const int m0 = blockIdx.x * 128;
  const int lane = tid & 63;
  const int wv = tid >> 6;
  const int l15 = lane & 15;
  const int g4 = lane >> 4;
  const int koff = g4 * 8;
  const int sr = tid >> 1;
  const int sc = (tid & 1) * 16;
  const bool rowok = (m0 + sr) < M;

  #pragma unroll
  for (int ks = 0; ks < 4; ++ks) {
    uint4 h0 = {0, 0, 0, 0}, h1 = {0, 0, 0, 0}, l0 = {0, 0, 0, 0}, l1 = {0, 0, 0, 0};
    if (rowok) {
      const u16* ap = Ahg + (size_t)(m0 + sr) * 128 + ks * 32 + sc;
      h0 = *(const uint4*)ap;
      h1 = *(const uint4*)(ap + 8);
      const u16* lp = Alg + (size_t)(m0 + sr) * 128 + ks * 32 + sc;
      l0 = *(const uint4*)lp;
      l1 = *(const uint4*)(lp + 8);
    }
    *(uint4*)&Ah[ks][sr][sc] = h0;
    *(uint4*)&Ah[ks][sr][sc + 8] = h1;
    *(uint4*)&Al[ks][sr][sc] = l0;
    *(uint4*)&Al[ks][sr][sc + 8] = l1;
  }
  __syncthreads();

  #pragma unroll
  for (int s = 0; s < NSLAB; ++s) {
    f32x4 acc[2][8];
    #pragma unroll
    for (int mi = 0; mi < 2; ++mi)
      #pragma unroll
      for (int ni = 0; ni < 8; ++ni) acc[mi][ni] = (f32x4){0.f, 0.f, 0.f, 0.f};

    #pragma unroll
    for (int ks = 0; ks < 4; ++ks) {
      bf16x8 a_h[2], a_l[2];
      #pragma unroll
      for (int mi = 0; mi < 2; ++mi) {
        int row = wv * 32 + mi * 16 + l15;
        a_h[mi] = *(const bf16x8*)&Ah[ks][row][koff];
        a_l[mi] = *(const bf16x8*)&Al[ks][row][koff];
      }
      #pragma unroll
      for (int ni = 0; ni < 8; ++ni) {
        size_t boff = (size_t)(s * 128 + ni * 16 + l15) * 128 + ks * 32 + koff;
        bf16x8 b_h = *(const bf16x8*)(Bth + boff);
        bf16x8 b_l = *(const bf16x8*)(Btl + boff);
        #pragma unroll
        for (int mi = 0; mi < 2; ++mi) {
          acc[mi][ni] = __builtin_amdgcn_mfma_f32_16x16x32_bf16(a_h[mi], b_h, acc[mi][ni], 0, 0, 0);
          acc[mi][ni] = __builtin_amdgcn_mfma_f32_16x16x32_bf16(a_l[mi], b_h, acc[mi][ni], 0, 0, 0);
          acc[mi][ni] = __builtin_amdgcn_mfma_f32_16x16x32_bf16(a_h[mi], b_l, acc[mi][ni], 0, 0, 0);
        }
      }
    }

    void* cp = dst.p[s];
    int ld = dst.ld[s], cb = dst.cb[s], isb = dst.isbf[s];
    #pragma unroll
    for (int mi = 0; mi < 2; ++mi) {
      #pragma unroll
      for (int ni = 0; ni < 8; ++ni) {
        int colL = ni * 16 + l15;
        float bi = bias[s * 128 + colL];
        int rbase = m0 + wv * 32 + mi * 16 + g4 * 4;
        #pragma unroll
        for (int rr = 0; rr < 4; ++rr) {
          int row = rbase + rr;
          if (row >= M) continue;
          float o = acc[mi][ni][rr] + bi;
          if (isb)
            ((u16*)cp)[(size_t)row * ld + cb + colL] = bf16_rne(o);
          else
            ((float*)cp)[(size_t)row * ld + cb + colL] = o;
        }
      }
    }
  }
}

// ---------------- f32-A GEMM (input projections, a-projection), writes split pair ----------------
template <int MODE, int GIN>  // MODE 1: relu, 2: skip-gate
__global__ __launch_bounds__(256) void gemm_af32(
    const float* __restrict__ A32, const u16* __restrict__ Bth, const u16* __restrict__ Btl,
    const float* __restrict__ bias, u16* __restrict__ Ch, u16* __restrict__ Cl,
    const u16* __restrict__ Xoh, const u16* __restrict__ Xol,
    const float* __restrict__ skip_p, int M, int K, int Kp) {
  __shared__ u16 Ah[128][40];
  __shared__ u16 Al[128][40];
  __shared__ u16 Bh[128][40];
  __shared__ u16 Bl[128][40];
  const int tid = threadIdx.x;
  const int m0 = blockIdx.x * 128;
  const int lane = tid & 63;
  const int wv = tid >> 6;
  const int l15 = lane & 15;
  const int koff = (lane >> 4) * 8;
  const int sr = tid >> 1;
  const int sc = (tid & 1) * 16;
  const bool rowok = (m0 + sr) < M;

  f32x4 acc[2][8];
  #pragma unroll
  for (int mi = 0; mi < 2; ++mi)
    #pragma unroll
    for (int ni = 0; ni < 8; ++ni) acc[mi][ni] = (f32x4){0.f, 0.f, 0.f, 0.f};

  for (int k0 = 0; k0 < K; k0 += 32) {
    float va[16];
    if (rowok && (k0 + 32 <= K)) {
      const float* ap = A32 + (size_t)(m0 + sr) * K + k0 + sc;
      #pragma unroll
      for (int j = 0; j < 4; ++j) {
        float4 f = *(const float4*)(ap + 4 * j);
        va[4 * j + 0] = f.x; va[4 * j + 1] = f.y; va[4 * j + 2] = f.z; va[4 * j + 3] = f.w;
      }
    } else {
      #pragma unroll
      for (int j = 0; j < 16; ++j) {
        int kc = k0 + sc + j;
        va[j] = (rowok && kc < K) ? A32[(size_t)(m0 + sr) * K + kc] : 0.0f;
      }
    }
    alignas(16) u16 hv[16];
    alignas(16) u16 lv[16];
    #pragma unroll
    for (int j = 0; j < 16; ++j) {
      float x = GIN ? gelu_f(va[j]) : va[j];
      split2(x, hv[j], lv[j]);
    }
    *(uint4*)&Ah[sr][sc] = *(const uint4*)&hv[0];
    *(uint4*)&Ah[sr][sc + 8] = *(const uint4*)&hv[8];
    *(uint4*)&Al[sr][sc] = *(const uint4*)&lv[0];
    *(uint4*)&Al[sr][sc + 8] = *(const uint4*)&lv[8];
    {
      const u16* bp = Bth + (size_t)sr * Kp + k0 + sc;
      *(uint4*)&Bh[sr][sc] = *(const uint4*)bp;
      *(uint4*)&Bh[sr][sc + 8] = *(const uint4*)(bp + 8);
      const u16* lp = Btl + (size_t)sr * Kp + k0 + sc;
      *(uint4*)&Bl[sr][sc] = *(const uint4*)lp;
      *(uint4*)&Bl[sr][sc + 8] = *(const uint4*)(lp + 8);
    }
    __syncthreads();

    bf16x8 a_h[2], a_l[2];
    #pragma unroll
    for (int mi = 0; mi < 2; ++mi) {
      int row = wv * 32 + mi * 16 + l15;
      a_h[mi] = *(const bf16x8*)&Ah[row][koff];
      a_l[mi] = *(const bf16x8*)&Al[row][koff];
    }
    #pragma unroll
    for (int ni = 0; ni < 8; ++ni) {
      int col = ni * 16 + l15;
      bf16x8 b_h = *(const bf16x8*)&Bh[col][koff];
      bf16x8 b_l = *(const bf16x8*)&Bl[col][koff];
      #pragma unroll
      for (int mi = 0; mi < 2; ++mi) {
        acc[mi][ni] = __builtin_amdgcn_mfma_f32_16x16x32_bf16(a_h[mi], b_h, acc[mi][ni], 0, 0, 0);
        acc[mi][ni] = __builtin_amdgcn_mfma_f32_16x16x32_bf16(a_l[mi], b_h, acc[mi][ni], 0, 0, 0);
        acc[mi][ni] = __builtin_amdgcn_mfma_f32_16x16x32_bf16(a_h[mi], b_l, acc[mi][ni], 0, 0, 0);
      }
    }
    __syncthreads();
  }

  float g = 1.0f;
  if (MODE == 2) g = 1.0f / (1.0f + __expf(-skip_p[0]));

  #pragma unroll
  for (int mi = 0; mi < 2; ++mi) {
    #pragma unroll
    for (int ni = 0; ni < 8; ++ni) {
      int colL = ni * 16 + l15;
      float bi = bias[colL];
      int rbase = m0 + wv * 32 + mi * 16 + (lane >> 4) * 4;
      #pragma unroll
      for (int rr = 0; rr < 4; ++rr) {
        int row = rbase + rr;
        if (row >= M) continue;
        float o = acc[mi][ni][rr] + bi;
        if (MODE == 1) o = fmaxf(o, 0.0f);
        if (MODE == 2) {
          float xo = bf16_to_f(Xoh[(size_t)row * 128 + colL]) + bf16_to_f(Xol[(size_t)row * 128 + colL]);
          o = g * o + (1.0f - g) * xo;
        }
        u16 hh, ll;
        split2(o, hh, ll);
        Ch[(size_t)row * 128 + colL] = hh;
        Cl[(size_t)row * 128 + colL] = ll;
      }
    }
  }
}

// ---------------- fused attention: bf16 kv rows (512B), one wave per dst node ----------------
// lanes 0-31: k-side (+q, f32); lanes 32-63: v-side. Lane loads kv[s][4*lane..+3] (8B).
template <int NET>
__global__ __launch_bounds__(256) void attn_fused(
    const float* __restrict__ q,
    const u16* __restrict__ kv0, const u16* __restrict__ kv1,
    const int* __restrict__ ptr0, const int* __restrict__ ptr1,
    const int* __restrict__ srcs,
    float* __restrict__ agg, int Ndst) {
  int wave = threadIdx.x >> 6;
  int lane = threadIdx.x & 63;
  int n = blockIdx.x * 4 + wave;
  if (n >= Ndst) return;
  float4 q4 = make_float4(0.f, 0.f, 0.f, 0.f);
  if (lane < 32) q4 = *(const float4*)&q[(size_t)n * 128 + lane * 4];
  float4 total = make_float4(0.f, 0.f, 0.f, 0.f);

  #pragma unroll
  for (int et = 0; et < NET; ++et) {
    const u16* kv = (et == 0) ? kv0 : kv1;
    const int* ptr = (et == 0) ? ptr0 : ptr1;
    int start = ptr[n], end = ptr[n + 1];
    float mx = -3.0e38f, sum = 0.0f;
    float4 acc = make_float4(0.f, 0.f, 0.f, 0.f);
    for (int e = start; e < end; e += 4) {
      int nb = end - e;
      nb = nb > 4 ? 4 : nb;
      int sA[4];
      #pragma unroll
      for (int j = 0; j < 4; ++j) {
        int ee = e + j;
        ee = (ee < end - 1) ? ee : (end - 1);
        sA[j] = srcs[ee];
      }
      float4 r[4];
      #pragma unroll
      for (int j = 0; j < 4; ++j) {
        uint2 u = *(const uint2*)&kv[(size_t)sA[j] * 256 + lane * 4];
        r[j].x = bf16_to_f((u16)(u.x & 0xffffu));
        r[j].y = bf16_to_f((u16)(u.x >> 16));
        r[j].z = bf16_to_f((u16)(u.y & 0xffffu));
        r[j].w = bf16_to_f((u16)(u.y >> 16));
      }
      #pragma unroll
      for (int j = 0; j < 4; ++j) {
        if (j < nb) {  // wave-uniform
          float p = q4.x * r[j].x + q4.y * r[j].y + q4.z * r[j].z + q4.w * r[j].w;
          p += __shfl_xor(p, 1);
          p += __shfl_xor(p, 2);
          p += __shfl_xor(p, 4);
          float mxn = fmaxf(mx, p);
          float scale = __expf(mx - mxn);
          float w = __expf(p - mxn);
          sum = sum * scale + w;
          mx = mxn;
          float scB = __shfl(scale, lane & 31);
          float wB = __shfl(w, lane & 31);
          acc.x = acc.x * scB + wB * r[j].x;
          acc.y = acc.y * scB + wB * r[j].y;
          acc.z = acc.z * scB + wB * r[j].z;
          acc.w = acc.w * scB + wB * r[j].w;
        }
      }
    }
    float invB = __shfl(1.0f / (sum + 1e-16f), lane & 31);
    total.x += acc.x * invB;
    total.y += acc.y * invB;
    total.z += acc.z * invB;
    total.w += acc.w * invB;
  }
  if (lane >= 32)
    *(float4*)&agg[(size_t)n * 128 + (lane - 32) * 4] = total;
}

// ---------------- final projection ----------------
__global__ __launch_bounds__(256) void gemm_out(const u16* __restrict__ Xh,
                                                const u16* __restrict__ Xl,
                                                const float* __restrict__ W,
                                                const float* __restrict__ b,
                                                float* __restrict__ out, int M) {
  __shared__ float Ws[1024];
  __shared__ float As[32][129];
  int tid = threadIdx.x;
  int m0 = blockIdx.x * 32;
  *(float4*)&Ws[tid * 4] = *(const float4*)&W[tid * 4];
  {
    int r = tid >> 3;
    int c0 = (tid & 7) * 16;
    if (m0 + r < M) {
      const u16* hp = Xh + (size_t)(m0 + r) * 128 + c0;
      const u16* lp = Xl + (size_t)(m0 + r) * 128 + c0;
      #pragma unroll
      for (int j = 0; j < 16; ++j) As[r][c0 + j] = bf16_to_f(hp[j]) + bf16_to_f(lp[j]);
    } else {
      #pragma unroll
      for (int j = 0; j < 16; ++j) As[r][c0 + j] = 0.0f;
    }
  }
  __syncthreads();
  int r = tid >> 3, c = tid & 7;
  float sum = b[c];
  #pragma unroll 16
  for (int k = 0; k < 128; ++k) sum = fmaf(As[r][k], Ws[k * 8 + c], sum);
  if (m0 + r < M) out[(size_t)(m0 + r) * 8 + c] = sum;
}

// ---------------- host orchestration ----------------
static inline size_t align256(size_t x) { return (x + 255) & ~(size_t)255; }

extern "C" void kernel_launch(void* const* d_in, const int* in_sizes, int n_in,
                              void* d_out, int out_size, void* d_ws, size_t ws_size,
                              hipStream_t stream) {
  const float* x_context = (const float*)d_in[0];
  const float* x_question = (const float*)d_in[1];
  const int* src_q2c = (const int*)d_in[2];
  const int* dst_q2c = (const int*)d_in[3];
  const int* src_c2c = (const int*)d_in[4];
  const int* dst_c2c = (const int*)d_in[5];
  const int* src_c2q = (const int*)d_in[6];
  const int* dst_c2q = (const int*)d_in[7];
  const float* inWc = (const float*)d_in[8];
  const float* inbc = (const float*)d_in[9];
  const float* inWq = (const float*)d_in[10];
  const float* inbq = (const float*)d_in[11];
  const float* kW = (const float*)d_in[12];
  const float* kB = (const float*)d_in[13];
  const float* qW = (const float*)d_in[14];
  const float* qB = (const float*)d_in[15];
  const float* vW = (const float*)d_in[16];
  const float* vB = (const float*)d_in[17];
  const float* aW = (const float*)d_in[18];
  const float* aB = (const float*)d_in[19];
  const float* skip = (const float*)d_in[20];
  const float* arel = (const float*)d_in[21];
  const float* mrel = (const float*)d_in[22];
  const float* prel = (const float*)d_in[23];
  const float* outW = (const float*)d_in[24];
  const float* outb = (const float*)d_in[25];

  char* base = (char*)d_ws;
  size_t off = 0;
  auto carve = [&](size_t bytes) -> void* {
    void* p = base + off;
    off = align256(off + bytes);
    return p;
  };
  u16* x0h = (u16*)carve((size_t)NC * 128 * 2);
  u16* x0l = (u16*)carve((size_t)NC * 128 * 2);
  u16* x1h = (u16*)carve((size_t)NQ * 128 * 2);
  u16* x1l = (u16*)carve((size_t)NQ * 128 * 2);
  float* q0 = (float*)carve((size_t)NC * 128 * 4);
  float* q1 = (float*)carve((size_t)NQ * 128 * 4);
  u16* kvA = (u16*)carve((size_t)NQ * 256 * 2);    // et0: question-src k|v (bf16)
  u16* kvB1 = (u16*)carve((size_t)NC * 256 * 2);   // et1: context-src k|v
  u16* kvB2 = (u16*)carve((size_t)NC * 256 * 2);   // et2: context-src k|v
  float* agg0 = (float*)carve((size_t)NC * 128 * 4);
  float* agg1 = (float*)carve((size_t)NQ * 128 * 4);
  u16* Bth = (u16*)carve((size_t)640 * 768 * 2);
  u16* Btl = (u16*)carve((size_t)640 * 768 * 2);
  float* biasBuf = (float*)carve(1024 * 4);
  int* ptr_all = (int*)carve((size_t)(NTOT + 1) * 4);
  int* srcs_all = (int*)carve((size_t)3 * NEDGE * 4);
  int* counts = (int*)carve((size_t)NTOT * 4);
  int* cursor = (int*)carve((size_t)NTOT * 4);
  int* blksums = (int*)carve(2048 * 4);

  // ---- fused CSR build ----
  {
    int nb = (NTOT + 255) / 256;
    hipMemsetAsync(counts, 0, (size_t)NTOT * 4, stream);
    k_count3<<<(3 * NEDGE + 255) / 256, 256, 0, stream>>>(dst_q2c, dst_c2c, dst_c2q, counts);
    k_scan_block<<<nb, 256, 0, stream>>>(counts, ptr_all, blksums, NTOT);
    k_scan_sums<<<1, 1024, 0, stream>>>(blksums, nb);
    k_scan_add<<<nb, 256, 0, stream>>>(ptr_all, blksums, NTOT, 3 * NEDGE);
    k_copy<<<nb, 256, 0, stream>>>(cursor, ptr_all, NTOT);
    k_scatter3<<<(3 * NEDGE + 255) / 256, 256, 0, stream>>>(
        src_q2c, src_c2c, src_c2q, dst_q2c, dst_c2c, dst_c2q, cursor, srcs_all);
  }
  const int* ptr_et0 = ptr_all;
  const int* ptr_et1 = ptr_all + NC;
  const int* ptr_et2 = ptr_all + 2 * NC;

  // ---- input projections ----
  split_w<<<128, 256, 0, stream>>>(inWc, inbc, Bth, Btl, biasBuf, FC, 320);
  gemm_af32<1, 0><<<(NC + 127) / 128, 256, 0, stream>>>(
      x_context, Bth, Btl, biasBuf, x0h, x0l, nullptr, nullptr, nullptr, NC, FC, 320);
  split_w<<<128, 256, 0, stream>>>(inWq, inbq, Bth, Btl, biasBuf, FQ, 768);
  gemm_af32<1, 0><<<(NQ + 127) / 128, 256, 0, stream>>>(
      x_question, Bth, Btl, biasBuf, x1h, x1l, nullptr, nullptr, nullptr, NQ, FQ, 768);

  u16* xh[2] = {x0h, x1h};
  u16* xl[2] = {x0l, x1l};
  float* aggs[2] = {agg0, agg1};
  const int NsArr[2] = {NC, NQ};

  for (int l = 0; l < 2; ++l) {
    size_t lw = (size_t)l * 2 * 16384;  // weights for (l, nt=0)
    size_t lb = (size_t)l * 2 * 128;
    size_t le = (size_t)l * 3 * 4096;   // rel for (l, et=0)
    size_t lp = (size_t)l * 3 * 4;

    // B for x0: [q(l,0) | k_et1 | v_et1 | k_et2 | v_et2]
    prep_B<<<dim3(128, 5), 128, 0, stream>>>(
        qW + lw, qB + lb, kW + lw, kB + lb, vW + lw, vB + lb,
        arel + le + 4096, mrel + le + 4096, prel + lp + 4,
        arel + le + 8192, mrel + le + 8192, prel + lp + 8,
        Bth, Btl, biasBuf);
    {
      PDst cd = {{q0, kvB1, kvB1, kvB2, kvB2}, {128, 256, 256, 256, 256},
                 {0, 0, 128, 0, 128}, {0, 1, 1, 1, 1}};
      proj_gemm<5><<<(NC + 127) / 128, 256, 0, stream>>>(x0h, x0l, Bth, Btl, biasBuf, cd, NC);
    }
    // B for x1: [q(l,1) | k_et0 | v_et0]
    prep_B<<<dim3(128, 3), 128, 0, stream>>>(
        qW + lw + 16384, qB + lb + 128, kW + lw + 16384, kB + lb + 128,
        vW + lw + 16384, vB + lb + 128,
        arel + le, mrel + le, prel + lp,
        nullptr, nullptr, nullptr,
        Bth, Btl, biasBuf);
    {
      PDst cd = {{q1, kvA, kvA, nullptr, nullptr}, {128, 256, 256, 0, 0},
                 {0, 0, 128, 0, 0}, {0, 1, 1, 0, 0}};
      proj_gemm<3><<<(NQ + 127) / 128, 256, 0, stream>>>(x1h, x1l, Bth, Btl, biasBuf, cd, NQ);
    }
    // attention
    attn_fused<2><<<(NC + 3) / 4, 256, 0, stream>>>(q0, kvA, kvB1, ptr_et0, ptr_et1,
                                                    srcs_all, agg0, NC);
    attn_fused<1><<<(NQ + 3) / 4, 256, 0, stream>>>(q1, kvB2, nullptr, ptr_et2, nullptr,
                                                    srcs_all, agg1, NQ);
    // a-projections: gelu(agg) @ aW + skip-gate -> x pair
    for (int nt = 0; nt < 2; ++nt) {
      split_w<<<128, 256, 0, stream>>>(aW + lw + (size_t)nt * 16384,
                                       aB + lb + (size_t)nt * 128, Bth, Btl, biasBuf, 128, 128);
      gemm_af32<2, 1><<<(NsArr[nt] + 127) / 128, 256, 0, stream>>>(
          aggs[nt], Bth, Btl, biasBuf, xh[nt], xl[nt], xh[nt], xl[nt],
          skip + l * 2 + nt, NsArr[nt], 128, 128);
    }
  }

  gemm_out<<<(NC + 31) / 32, 256, 0, stream>>>(x0h, x0l, outW, outb, (float*)d_out, NC);
}

// Round 5
// 1078.454 us; speedup vs baseline: 1.4344x; 1.4344x over previous
//
#include <hip/hip_runtime.h>

constexpr int NC = 100000;
constexpr int NQ = 20000;
constexpr int FC = 300;
constexpr int FQ = 768;
constexpr int NEDGE = 400000;
constexpr int NTOT = NC + NC + NQ;  // concatenated dst segments: et0 | et1 | et2
constexpr float SCALE = 0.17677669529663687f;  // 1/sqrt(32)

typedef __attribute__((ext_vector_type(8))) short bf16x8;
typedef __attribute__((ext_vector_type(4))) float f32x4;
typedef unsigned short u16;

struct PDst {
  void* p[5];
  int ld[5];
  int cb[5];
  int isbf[5];
};

__device__ __forceinline__ float gelu_f(float x) {
  return 0.5f * x * (1.0f + erff(x * 0.7071067811865476f));
}
__device__ __forceinline__ u16 bf16_rne(float x) {
  unsigned u = __float_as_uint(x);
  unsigned r = u + 0x7fffu + ((u >> 16) & 1u);
  return (u16)(r >> 16);
}
__device__ __forceinline__ float bf16_to_f(u16 h) {
  return __uint_as_float(((unsigned)h) << 16);
}
__device__ __forceinline__ void split2(float x, u16& hi, u16& lo) {
  hi = bf16_rne(x);
  lo = bf16_rne(x - bf16_to_f(hi));
}

// ---------------- fused CSR build over 3 edge types ----------------
__global__ void k_count3(const int* __restrict__ d0, const int* __restrict__ d1,
                         const int* __restrict__ d2, int* __restrict__ counts) {
  int i = blockIdx.x * 256 + threadIdx.x;
  if (i >= 3 * NEDGE) return;
  int et = i / NEDGE, e = i - et * NEDGE;
  int d = (et == 0) ? d0[e] : (et == 1) ? d1[e] : d2[e];
  int base = (et == 0) ? 0 : (et == 1) ? NC : 2 * NC;
  atomicAdd(&counts[base + d], 1);
}

__global__ void k_scan_block(const int* __restrict__ in, int* __restrict__ out,
                             int* __restrict__ bsum, int n) {
  __shared__ int s[256];
  int tid = threadIdx.x;
  int i = blockIdx.x * 256 + tid;
  int v = (i < n) ? in[i] : 0;
  s[tid] = v;
  __syncthreads();
  for (int off = 1; off < 256; off <<= 1) {
    int t = (tid >= off) ? s[tid - off] : 0;
    __syncthreads();
    s[tid] += t;
    __syncthreads();
  }
  if (i < n) out[i] = s[tid] - v;
  if (tid == 255) bsum[blockIdx.x] = s[255];
}

__global__ void k_scan_sums(int* __restrict__ bsum, int nb) {
  __shared__ int s[1024];
  int tid = threadIdx.x;
  int v = (tid < nb) ? bsum[tid] : 0;
  s[tid] = v;
  __syncthreads();
  for (int off = 1; off < 1024; off <<= 1) {
    int t = (tid >= off) ? s[tid - off] : 0;
    __syncthreads();
    s[tid] += t;
    __syncthreads();
  }
  if (tid < nb) bsum[tid] = s[tid] - v;
}

__global__ void k_scan_add(int* __restrict__ ptr, const int* __restrict__ bsum, int n, int total) {
  int i = blockIdx.x * 256 + threadIdx.x;
  if (i < n) ptr[i] += bsum[blockIdx.x];
  if (i == 0) ptr[n] = total;
}

__global__ void k_copy(int* __restrict__ dst, const int* __restrict__ src, int n) {
  int i = blockIdx.x * 256 + threadIdx.x;
  if (i < n) dst[i] = src[i];
}

__global__ void k_scatter3(const int* __restrict__ s0, const int* __restrict__ s1,
                           const int* __restrict__ s2, const int* __restrict__ d0,
                           const int* __restrict__ d1, const int* __restrict__ d2,
                           int* __restrict__ cursor, int* __restrict__ srcs_out) {
  int i = blockIdx.x * 256 + threadIdx.x;
  if (i >= 3 * NEDGE) return;
  int et = i / NEDGE, e = i - et * NEDGE;
  int d = (et == 0) ? d0[e] : (et == 1) ? d1[e] : d2[e];
  int sv = (et == 0) ? s0[e] : (et == 1) ? s1[e] : s2[e];
  int base = (et == 0) ? 0 : (et == 1) ? NC : 2 * NC;
  int p = atomicAdd(&cursor[base + d], 1);
  srcs_out[p] = sv;
}

// ---------------- per-layer B preparation: q split + 2 or 4 rel-folds ----------------
__global__ void prep_B(const float* __restrict__ Wq, const float* __restrict__ bq,
                       const float* __restrict__ Wk, const float* __restrict__ bk,
                       const float* __restrict__ Wv, const float* __restrict__ bv,
                       const float* __restrict__ relA0, const float* __restrict__ relM0,
                       const float* __restrict__ prel0,
                       const float* __restrict__ relA1, const float* __restrict__ relM1,
                       const float* __restrict__ prel1,
                       u16* __restrict__ Bth, u16* __restrict__ Btl,
                       float* __restrict__ biasOut) {
  int i = blockIdx.x;     // input dim (k) 0..127
  int col = threadIdx.x;  // output col 0..127
  int y = blockIdx.y;
  if (y == 0) {
    float v = Wq[i * 128 + col];
    u16 hi, lo;
    split2(v, hi, lo);
    Bth[(size_t)col * 128 + i] = hi;
    Btl[(size_t)col * 128 + i] = lo;
    if (i == 0) biasOut[col] = bq[col];
    return;
  }
  int pair = (y - 1) >> 1;
  bool isK = ((y - 1) & 1) == 0;
  const float* W = isK ? Wk : Wv;
  const float* bb = isK ? bk : bv;
  const float* rel = isK ? (pair ? relA1 : relA0) : (pair ? relM1 : relM0);
  const float* pr = isK ? (pair ? prel1 : prel0) : nullptr;
  int h = col >> 5, f = col & 31;
  float m = (pr ? pr[h] : 1.0f) * (isK ? SCALE : 1.0f);
  float s = 0.0f;
  #pragma unroll
  for (int d = 0; d < 32; ++d)
    s += W[i * 128 + h * 32 + d] * rel[(h * 32 + d) * 32 + f];
  s *= m;
  u16 hi, lo;
  split2(s, hi, lo);
  int colOff = y * 128;
  Bth[(size_t)(colOff + col) * 128 + i] = hi;
  Btl[(size_t)(colOff + col) * 128 + i] = lo;
  if (i == 0) {
    float sb = 0.0f;
    #pragma unroll
    for (int d = 0; d < 32; ++d)
      sb += bb[h * 32 + d] * rel[(h * 32 + d) * 32 + f];
    biasOut[colOff + col] = sb * m;
  }
}

// ---------------- split+transpose plain weight W[KxN(=128)] -> Bt[N x Kp] ----------------
__global__ void split_w(const float* __restrict__ W, const float* __restrict__ b,
                        u16* __restrict__ Bth, u16* __restrict__ Btl,
                        float* __restrict__ biasOut, int K, int Kp) {
  int n = blockIdx.x;
  for (int k = threadIdx.x; k < Kp; k += blockDim.x) {
    float v = (k < K) ? W[(size_t)k * 128 + n] : 0.0f;
    u16 hi, lo;
    split2(v, hi, lo);
    Bth[(size_t)n * Kp + k] = hi;
    Btl[(size_t)n * Kp + k] = lo;
  }
  if (threadIdx.x == 0) biasOut[n] = b[n];
}

// ---------------- K=128 slab GEMM: pre-split A, per-K-step LDS staging, slab-routed C ----------
// grid.y = slab; B rows [y*128, y*128+128) of Bth/Btl (Kp=128).
__global__ __launch_bounds__(256) void slab_gemm(
    const u16* __restrict__ Ahg, const u16* __restrict__ Alg,
    const u16* __restrict__ Bth, const u16* __restrict__ Btl,
    const float* __restrict__ bias, PDst dst, int M) {
  __shared__ u16 Ah[128][40];
  __shared__ u16 Al[128][40];
  __shared__ u16 Bh[128][40];
  __shared__ u16 Bl[128][40];
  const int tid = threadIdx.x;
  const int m0 = blockIdx.x * 128;
  const int nb0 = blockIdx.y * 128;  // B row base
  const int lane = tid & 63;
  const int wv = tid >> 6;
  const int l15 = lane & 15;
  const int g4 = lane >> 4;
  const int koff = g4 * 8;
  const int sr = tid >> 1;
  const int sc = (tid & 1) * 16;
  const bool rowok = (m0 + sr) < M;

  f32x4 acc[2][8];
  #pragma unroll
  for (int mi = 0; mi < 2; ++mi)
    #pragma unroll
    for (int ni = 0; ni < 8; ++ni) acc[mi][ni] = (f32x4){0.f, 0.f, 0.f, 0.f};

  for (int k0 = 0; k0 < 128; k0 += 32) {
    uint4 h0 = {0, 0, 0, 0}, h1 = {0, 0, 0, 0}, l0 = {0, 0, 0, 0}, l1 = {0, 0, 0, 0};
    if (rowok) {
      const u16* ap = Ahg + (size_t)(m0 + sr) * 128 + k0 + sc;
      h0 = *(const uint4*)ap;
      h1 = *(const uint4*)(ap + 8);
      const u16* lp = Alg + (size_t)(m0 + sr) * 128 + k0 + sc;
      l0 = *(const uint4*)lp;
      l1 = *(const uint4*)(lp + 8);
    }
    *(uint4*)&Ah[sr][sc] = h0;
    *(uint4*)&Ah[sr][sc + 8] = h1;
    *(uint4*)&Al[sr][sc] = l0;
    *(uint4*)&Al[sr][sc + 8] = l1;
    {
      const u16* bp = Bth + (size_t)(nb0 + sr) * 128 + k0 + sc;
      *(uint4*)&Bh[sr][sc] = *(const uint4*)bp;
      *(uint4*)&Bh[sr][sc + 8] = *(const uint4*)(bp + 8);
      const u16* lp = Btl + (size_t)(nb0 + sr) * 128 + k0 + sc;
      *(uint4*)&Bl[sr][sc] = *(const uint4*)lp;
      *(uint4*)&Bl[sr][sc + 8] = *(const uint4*)(lp + 8);
    }
    __syncthreads();

    bf16x8 a_h[2], a_l[2];
    #pragma unroll
    for (int mi = 0; mi < 2; ++mi) {
      int row = wv * 32 + mi * 16 + l15;
      a_h[mi] = *(const bf16x8*)&Ah[row][koff];
      a_l[mi] = *(const bf16x8*)&Al[row][koff];
    }
    #pragma unroll
    for (int ni = 0; ni < 8; ++ni) {
      int col = ni * 16 + l15;
      bf16x8 b_h = *(const bf16x8*)&Bh[col][koff];
      bf16x8 b_l = *(const bf16x8*)&Bl[col][koff];
      #pragma unroll
      for (int mi = 0; mi < 2; ++mi) {
        acc[mi][ni] = __builtin_amdgcn_mfma_f32_16x16x32_bf16(a_h[mi], b_h, acc[mi][ni], 0, 0, 0);
        acc[mi][ni] = __builtin_amdgcn_mfma_f32_16x16x32_bf16(a_l[mi], b_h, acc[mi][ni], 0, 0, 0);
        acc[mi][ni] = __builtin_amdgcn_mfma_f32_16x16x32_bf16(a_h[mi], b_l, acc[mi][ni], 0, 0, 0);
      }
    }
    __syncthreads();
  }

  void* cp = dst.p[blockIdx.y];
  int ld = dst.ld[blockIdx.y], cb = dst.cb[blockIdx.y], isb = dst.isbf[blockIdx.y];
  #pragma unroll
  for (int mi = 0; mi < 2; ++mi) {
    #pragma unroll
    for (int ni = 0; ni < 8; ++ni) {
      int colL = ni * 16 + l15;
      float bi = bias[nb0 + colL];
      int rbase = m0 + wv * 32 + mi * 16 + g4 * 4;
      #pragma unroll
      for (int rr = 0; rr < 4; ++rr) {
        int row = rbase + rr;
        if (row >= M) continue;
        float o = acc[mi][ni][rr] + bi;
        if (isb)
          ((u16*)cp)[(size_t)row * ld + cb + colL] = bf16_rne(o);
        else
          ((float*)cp)[(size_t)row * ld + cb + colL] = o;
      }
    }
  }
}

// ---------------- f32-A GEMM (input projections, a-projection), writes split pair ----------------
template <int MODE, int GIN>  // MODE 1: relu, 2: skip-gate
__global__ __launch_bounds__(256) void gemm_af32(
    const float* __restrict__ A32, const u16* __restrict__ Bth, const u16* __restrict__ Btl,
    const float* __restrict__ bias, u16* __restrict__ Ch, u16* __restrict__ Cl,
    const u16* __restrict__ Xoh, const u16* __restrict__ Xol,
    const float* __restrict__ skip_p, int M, int K, int Kp) {
  __shared__ u16 Ah[128][40];
  __shared__ u16 Al[128][40];
  __shared__ u16 Bh[128][40];
  __shared__ u16 Bl[128][40];
  const int tid = threadIdx.x;
  const int m0 = blockIdx.x * 128;
  const int lane = tid & 63;
  const int wv = tid >> 6;
  const int l15 = lane & 15;
  const int koff = (lane >> 4) * 8;
  const int sr = tid >> 1;
  const int sc = (tid & 1) * 16;
  const bool rowok = (m0 + sr) < M;

  f32x4 acc[2][8];
  #pragma unroll
  for (int mi = 0; mi < 2; ++mi)
    #pragma unroll
    for (int ni = 0; ni < 8; ++ni) acc[mi][ni] = (f32x4){0.f, 0.f, 0.f, 0.f};

  for (int k0 = 0; k0 < K; k0 += 32) {
    float va[16];
    if (rowok && (k0 + 32 <= K)) {
      const float* ap = A32 + (size_t)(m0 + sr) * K + k0 + sc;
      #pragma unroll
      for (int j = 0; j < 4; ++j) {
        float4 f = *(const float4*)(ap + 4 * j);
        va[4 * j + 0] = f.x; va[4 * j + 1] = f.y; va[4 * j + 2] = f.z; va[4 * j + 3] = f.w;
      }
    } else {
      #pragma unroll
      for (int j = 0; j < 16; ++j) {
        int kc = k0 + sc + j;
        va[j] = (rowok && kc < K) ? A32[(size_t)(m0 + sr) * K + kc] : 0.0f;
      }
    }
    alignas(16) u16 hv[16];
    alignas(16) u16 lv[16];
    #pragma unroll
    for (int j = 0; j < 16; ++j) {
      float x = GIN ? gelu_f(va[j]) : va[j];
      split2(x, hv[j], lv[j]);
    }
    *(uint4*)&Ah[sr][sc] = *(const uint4*)&hv[0];
    *(uint4*)&Ah[sr][sc + 8] = *(const uint4*)&hv[8];
    *(uint4*)&Al[sr][sc] = *(const uint4*)&lv[0];
    *(uint4*)&Al[sr][sc + 8] = *(const uint4*)&lv[8];
    {
      const u16* bp = Bth + (size_t)sr * Kp + k0 + sc;
      *(uint4*)&Bh[sr][sc] = *(const uint4*)bp;
      *(uint4*)&Bh[sr][sc + 8] = *(const uint4*)(bp + 8);
      const u16* lp = Btl + (size_t)sr * Kp + k0 + sc;
      *(uint4*)&Bl[sr][sc] = *(const uint4*)lp;
      *(uint4*)&Bl[sr][sc + 8] = *(const uint4*)(lp + 8);
    }
    __syncthreads();

    bf16x8 a_h[2], a_l[2];
    #pragma unroll
    for (int mi = 0; mi < 2; ++mi) {
      int row = wv * 32 + mi * 16 + l15;
      a_h[mi] = *(const bf16x8*)&Ah[row][koff];
      a_l[mi] = *(const bf16x8*)&Al[row][koff];
    }
    #pragma unroll
    for (int ni = 0; ni < 8; ++ni) {
      int col = ni * 16 + l15;
      bf16x8 b_h = *(const bf16x8*)&Bh[col][koff];
      bf16x8 b_l = *(const bf16x8*)&Bl[col][koff];
      #pragma unroll
      for (int mi = 0; mi < 2; ++mi) {
        acc[mi][ni] = __builtin_amdgcn_mfma_f32_16x16x32_bf16(a_h[mi], b_h, acc[mi][ni], 0, 0, 0);
        acc[mi][ni] = __builtin_amdgcn_mfma_f32_16x16x32_bf16(a_l[mi], b_h, acc[mi][ni], 0, 0, 0);
        acc[mi][ni] = __builtin_amdgcn_mfma_f32_16x16x32_bf16(a_h[mi], b_l, acc[mi][ni], 0, 0, 0);
      }
    }
    __syncthreads();
  }

  float g = 1.0f;
  if (MODE == 2) g = 1.0f / (1.0f + __expf(-skip_p[0]));

  #pragma unroll
  for (int mi = 0; mi < 2; ++mi) {
    #pragma unroll
    for (int ni = 0; ni < 8; ++ni) {
      int colL = ni * 16 + l15;
      float bi = bias[colL];
      int rbase = m0 + wv * 32 + mi * 16 + (lane >> 4) * 4;
      #pragma unroll
      for (int rr = 0; rr < 4; ++rr) {
        int row = rbase + rr;
        if (row >= M) continue;
        float o = acc[mi][ni][rr] + bi;
        if (MODE == 1) o = fmaxf(o, 0.0f);
        if (MODE == 2) {
          float xo = bf16_to_f(Xoh[(size_t)row * 128 + colL]) + bf16_to_f(Xol[(size_t)row * 128 + colL]);
          o = g * o + (1.0f - g) * xo;
        }
        u16 hh, ll;
        split2(o, hh, ll);
        Ch[(size_t)row * 128 + colL] = hh;
        Cl[(size_t)row * 128 + colL] = ll;
      }
    }
  }
}

// ---------------- fused attention: bf16 kv rows (512B), one wave per dst node ----------------
template <int NET>
__global__ __launch_bounds__(256) void attn_fused(
    const float* __restrict__ q,
    const u16* __restrict__ kv0, const u16* __restrict__ kv1,
    const int* __restrict__ ptr0, const int* __restrict__ ptr1,
    const int* __restrict__ srcs,
    float* __restrict__ agg, int Ndst) {
  int wave = threadIdx.x >> 6;
  int lane = threadIdx.x & 63;
  int n = blockIdx.x * 4 + wave;
  if (n >= Ndst) return;
  float4 q4 = make_float4(0.f, 0.f, 0.f, 0.f);
  if (lane < 32) q4 = *(const float4*)&q[(size_t)n * 128 + lane * 4];
  float4 total = make_float4(0.f, 0.f, 0.f, 0.f);

  #pragma unroll
  for (int et = 0; et < NET; ++et) {
    const u16* kv = (et == 0) ? kv0 : kv1;
    const int* ptr = (et == 0) ? ptr0 : ptr1;
    int start = ptr[n], end = ptr[n + 1];
    float mx = -3.0e38f, sum = 0.0f;
    float4 acc = make_float4(0.f, 0.f, 0.f, 0.f);
    for (int e = start; e < end; e += 4) {
      int nb = end - e;
      nb = nb > 4 ? 4 : nb;
      int sA[4];
      #pragma unroll
      for (int j = 0; j < 4; ++j) {
        int ee = e + j;
        ee = (ee < end - 1) ? ee : (end - 1);
        sA[j] = srcs[ee];
      }
      float4 r[4];
      #pragma unroll
      for (int j = 0; j < 4; ++j) {
        uint2 u = *(const uint2*)&kv[(size_t)sA[j] * 256 + lane * 4];
        r[j].x = bf16_to_f((u16)(u.x & 0xffffu));
        r[j].y = bf16_to_f((u16)(u.x >> 16));
        r[j].z = bf16_to_f((u16)(u.y & 0xffffu));
        r[j].w = bf16_to_f((u16)(u.y >> 16));
      }
      #pragma unroll
      for (int j = 0; j < 4; ++j) {
        if (j < nb) {  // wave-uniform
          float p = q4.x * r[j].x + q4.y * r[j].y + q4.z * r[j].z + q4.w * r[j].w;
          p += __shfl_xor(p, 1);
          p += __shfl_xor(p, 2);
          p += __shfl_xor(p, 4);
          float mxn = fmaxf(mx, p);
          float scale = __expf(mx - mxn);
          float w = __expf(p - mxn);
          sum = sum * scale + w;
          mx = mxn;
          float scB = __shfl(scale, lane & 31);
          float wB = __shfl(w, lane & 31);
          acc.x = acc.x * scB + wB * r[j].x;
          acc.y = acc.y * scB + wB * r[j].y;
          acc.z = acc.z * scB + wB * r[j].z;
          acc.w = acc.w * scB + wB * r[j].w;
        }
      }
    }
    float invB = __shfl(1.0f / (sum + 1e-16f), lane & 31);
    total.x += acc.x * invB;
    total.y += acc.y * invB;
    total.z += acc.z * invB;
    total.w += acc.w * invB;
  }
  if (lane >= 32)
    *(float4*)&agg[(size_t)n * 128 + (lane - 32) * 4] = total;
}

// ---------------- final projection ----------------
__global__ __launch_bounds__(256) void gemm_out(const u16* __restrict__ Xh,
                                                const u16* __restrict__ Xl,
                                                const float* __restrict__ W,
                                                const float* __restrict__ b,
                                                float* __restrict__ out, int M) {
  __shared__ float Ws[1024];
  __shared__ float As[32][129];
  int tid = threadIdx.x;
  int m0 = blockIdx.x * 32;
  *(float4*)&Ws[tid * 4] = *(const float4*)&W[tid * 4];
  {
    int r = tid >> 3;
    int c0 = (tid & 7) * 16;
    if (m0 + r < M) {
      const u16* hp = Xh + (size_t)(m0 + r) * 128 + c0;
      const u16* lp = Xl + (size_t)(m0 + r) * 128 + c0;
      #pragma unroll
      for (int j = 0; j < 16; ++j) As[r][c0 + j] = bf16_to_f(hp[j]) + bf16_to_f(lp[j]);
    } else {
      #pragma unroll
      for (int j = 0; j < 16; ++j) As[r][c0 + j] = 0.0f;
    }
  }
  __syncthreads();
  int r = tid >> 3, c = tid & 7;
  float sum = b[c];
  #pragma unroll 16
  for (int k = 0; k < 128; ++k) sum = fmaf(As[r][k], Ws[k * 8 + c], sum);
  if (m0 + r < M) out[(size_t)(m0 + r) * 8 + c] = sum;
}

// ---------------- host orchestration ----------------
static inline size_t align256(size_t x) { return (x + 255) & ~(size_t)255; }

extern "C" void kernel_launch(void* const* d_in, const int* in_sizes, int n_in,
                              void* d_out, int out_size, void* d_ws, size_t ws_size,
                              hipStream_t stream) {
  const float* x_context = (const float*)d_in[0];
  const float* x_question = (const float*)d_in[1];
  const int* src_q2c = (const int*)d_in[2];
  const int* dst_q2c = (const int*)d_in[3];
  const int* src_c2c = (const int*)d_in[4];
  const int* dst_c2c = (const int*)d_in[5];
  const int* src_c2q = (const int*)d_in[6];
  const int* dst_c2q = (const int*)d_in[7];
  const float* inWc = (const float*)d_in[8];
  const float* inbc = (const float*)d_in[9];
  const float* inWq = (const float*)d_in[10];
  const float* inbq = (const float*)d_in[11];
  const float* kW = (const float*)d_in[12];
  const float* kB = (const float*)d_in[13];
  const float* qW = (const float*)d_in[14];
  const float* qB = (const float*)d_in[15];
  const float* vW = (const float*)d_in[16];
  const float* vB = (const float*)d_in[17];
  const float* aW = (const float*)d_in[18];
  const float* aB = (const float*)d_in[19];
  const float* skip = (const float*)d_in[20];
  const float* arel = (const float*)d_in[21];
  const float* mrel = (const float*)d_in[22];
  const float* prel = (const float*)d_in[23];
  const float* outW = (const float*)d_in[24];
  const float* outb = (const float*)d_in[25];

  char* base = (char*)d_ws;
  size_t off = 0;
  auto carve = [&](size_t bytes) -> void* {
    void* p = base + off;
    off = align256(off + bytes);
    return p;
  };
  u16* x0h = (u16*)carve((size_t)NC * 128 * 2);
  u16* x0l = (u16*)carve((size_t)NC * 128 * 2);
  u16* x1h = (u16*)carve((size_t)NQ * 128 * 2);
  u16* x1l = (u16*)carve((size_t)NQ * 128 * 2);
  float* q0 = (float*)carve((size_t)NC * 128 * 4);
  float* q1 = (float*)carve((size_t)NQ * 128 * 4);
  u16* kvA = (u16*)carve((size_t)NQ * 256 * 2);    // et0: question-src k|v (bf16)
  u16* kvB1 = (u16*)carve((size_t)NC * 256 * 2);   // et1: context-src k|v
  u16* kvB2 = (u16*)carve((size_t)NC * 256 * 2);   // et2: context-src k|v
  float* agg0 = (float*)carve((size_t)NC * 128 * 4);
  float* agg1 = (float*)carve((size_t)NQ * 128 * 4);
  u16* Bth = (u16*)carve((size_t)640 * 768 * 2);
  u16* Btl = (u16*)carve((size_t)640 * 768 * 2);
  float* biasBuf = (float*)carve(1024 * 4);
  int* ptr_all = (int*)carve((size_t)(NTOT + 1) * 4);
  int* srcs_all = (int*)carve((size_t)3 * NEDGE * 4);
  int* counts = (int*)carve((size_t)NTOT * 4);
  int* cursor = (int*)carve((size_t)NTOT * 4);
  int* blksums = (int*)carve(2048 * 4);

  // ---- fused CSR build ----
  {
    int nb = (NTOT + 255) / 256;
    hipMemsetAsync(counts, 0, (size_t)NTOT * 4, stream);
    k_count3<<<(3 * NEDGE + 255) / 256, 256, 0, stream>>>(dst_q2c, dst_c2c, dst_c2q, counts);
    k_scan_block<<<nb, 256, 0, stream>>>(counts, ptr_all, blksums, NTOT);
    k_scan_sums<<<1, 1024, 0, stream>>>(blksums, nb);
    k_scan_add<<<nb, 256, 0, stream>>>(ptr_all, blksums, NTOT, 3 * NEDGE);
    k_copy<<<nb, 256, 0, stream>>>(cursor, ptr_all, NTOT);
    k_scatter3<<<(3 * NEDGE + 255) / 256, 256, 0, stream>>>(
        src_q2c, src_c2c, src_c2q, dst_q2c, dst_c2c, dst_c2q, cursor, srcs_all);
  }
  const int* ptr_et0 = ptr_all;
  const int* ptr_et1 = ptr_all + NC;
  const int* ptr_et2 = ptr_all + 2 * NC;

  // ---- input projections ----
  split_w<<<128, 256, 0, stream>>>(inWc, inbc, Bth, Btl, biasBuf, FC, 320);
  gemm_af32<1, 0><<<(NC + 127) / 128, 256, 0, stream>>>(
      x_context, Bth, Btl, biasBuf, x0h, x0l, nullptr, nullptr, nullptr, NC, FC, 320);
  split_w<<<128, 256, 0, stream>>>(inWq, inbq, Bth, Btl, biasBuf, FQ, 768);
  gemm_af32<1, 0><<<(NQ + 127) / 128, 256, 0, stream>>>(
      x_question, Bth, Btl, biasBuf, x1h, x1l, nullptr, nullptr, nullptr, NQ, FQ, 768);

  u16* xh[2] = {x0h, x1h};
  u16* xl[2] = {x0l, x1l};
  float* aggs[2] = {agg0, agg1};
  const int NsArr[2] = {NC, NQ};

  for (int l = 0; l < 2; ++l) {
    size_t lw = (size_t)l * 2 * 16384;  // weights for (l, nt=0)
    size_t lb = (size_t)l * 2 * 128;
    size_t le = (size_t)l * 3 * 4096;   // rel for (l, et=0)
    size_t lp = (size_t)l * 3 * 4;

    // B for x0: [q(l,0) | k_et1 | v_et1 | k_et2 | v_et2]
    prep_B<<<dim3(128, 5), 128, 0, stream>>>(
        qW + lw, qB + lb, kW + lw, kB + lb, vW + lw, vB + lb,
        arel + le + 4096, mrel + le + 4096, prel + lp + 4,
        arel + le + 8192, mrel + le + 8192, prel + lp + 8,
        Bth, Btl, biasBuf);
    {
      PDst cd = {{q0, kvB1, kvB1, kvB2, kvB2}, {128, 256, 256, 256, 256},
                 {0, 0, 128, 0, 128}, {0, 1, 1, 1, 1}};
      slab_gemm<<<dim3((NC + 127) / 128, 5), 256, 0, stream>>>(x0h, x0l, Bth, Btl, biasBuf, cd, NC);
    }
    // B for x1: [q(l,1) | k_et0 | v_et0]
    prep_B<<<dim3(128, 3), 128, 0, stream>>>(
        qW + lw + 16384, qB + lb + 128, kW + lw + 16384, kB + lb + 128,
        vW + lw + 16384, vB + lb + 128,
        arel + le, mrel + le, prel + lp,
        nullptr, nullptr, nullptr,
        Bth, Btl, biasBuf);
    {
      PDst cd = {{q1, kvA, kvA, nullptr, nullptr}, {128, 256, 256, 0, 0},
                 {0, 0, 128, 0, 0}, {0, 1, 1, 0, 0}};
      slab_gemm<<<dim3((NQ + 127) / 128, 3), 256, 0, stream>>>(x1h, x1l, Bth, Btl, biasBuf, cd, NQ);
    }
    // attention
    attn_fused<2><<<(NC + 3) / 4, 256, 0, stream>>>(q0, kvA, kvB1, ptr_et0, ptr_et1,
                                                    srcs_all, agg0, NC);
    attn_fused<1><<<(NQ + 3) / 4, 256, 0, stream>>>(q1, kvB2, nullptr, ptr_et2, nullptr,
                                                    srcs_all, agg1, NQ);
    // a-projections: gelu(agg) @ aW + skip-gate -> x pair
    for (int nt = 0; nt < 2; ++nt) {
      split_w<<<128, 256, 0, stream>>>(aW + lw + (size_t)nt * 16384,
                                       aB + lb + (size_t)nt * 128, Bth, Btl, biasBuf, 128, 128);
      gemm_af32<2, 1><<<(NsArr[nt] + 127) / 128, 256, 0, stream>>>(
          aggs[nt], Bth, Btl, biasBuf, xh[nt], xl[nt], xh[nt], xl[nt],
          skip + l * 2 + nt, NsArr[nt], 128, 128);
    }
  }

  gemm_out<<<(NC + 31) / 32, 256, 0, stream>>>(x0h, x0l, outW, outb, (float*)d_out, NC);
}

// Round 6
// 980.888 us; speedup vs baseline: 1.5770x; 1.0995x over previous
//
#include <hip/hip_runtime.h>

constexpr int NC = 100000;
constexpr int NQ = 20000;
constexpr int FC = 300;
constexpr int FQ = 768;
constexpr int NEDGE = 400000;
constexpr int NTOT = NC + NC + NQ;   // concatenated dst segments: et0 | et1 | et2
constexpr int NTOT2 = NC + NQ;       // all nodes (context then question)
constexpr int NB0 = (NC + 127) / 128;  // 782
constexpr int NB1 = (NQ + 127) / 128;  // 157
constexpr int NBALL = NB0 + NB1;       // 939
constexpr float SCALE = 0.17677669529663687f;  // 1/sqrt(32)
constexpr float LOG2E = 1.4426950408889634f;

typedef __attribute__((ext_vector_type(8))) short bf16x8;
typedef __attribute__((ext_vector_type(4))) float f32x4;
typedef unsigned short u16;

__device__ __forceinline__ float gelu_f(float x) {
  return 0.5f * x * (1.0f + erff(x * 0.7071067811865476f));
}
__device__ __forceinline__ u16 bf16_rne(float x) {
  unsigned u = __float_as_uint(x);
  unsigned r = u + 0x7fffu + ((u >> 16) & 1u);
  return (u16)(r >> 16);
}
__device__ __forceinline__ float bf16_to_f(u16 h) {
  return __uint_as_float(((unsigned)h) << 16);
}
__device__ __forceinline__ void split2(float x, u16& hi, u16& lo) {
  hi = bf16_rne(x);
  lo = bf16_rne(x - bf16_to_f(hi));
}

// ---------------- fused CSR build over 3 edge types ----------------
__global__ void k_count3(const int* __restrict__ d0, const int* __restrict__ d1,
                         const int* __restrict__ d2, int* __restrict__ counts) {
  int i = blockIdx.x * 256 + threadIdx.x;
  if (i >= 3 * NEDGE) return;
  int et = i / NEDGE, e = i - et * NEDGE;
  int d = (et == 0) ? d0[e] : (et == 1) ? d1[e] : d2[e];
  int base = (et == 0) ? 0 : (et == 1) ? NC : 2 * NC;
  atomicAdd(&counts[base + d], 1);
}

__global__ void k_scan_block(const int* __restrict__ in, int* __restrict__ out,
                             int* __restrict__ bsum, int n) {
  __shared__ int s[256];
  int tid = threadIdx.x;
  int i = blockIdx.x * 256 + tid;
  int v = (i < n) ? in[i] : 0;
  s[tid] = v;
  __syncthreads();
  for (int off = 1; off < 256; off <<= 1) {
    int t = (tid >= off) ? s[tid - off] : 0;
    __syncthreads();
    s[tid] += t;
    __syncthreads();
  }
  if (i < n) out[i] = s[tid] - v;
  if (tid == 255) bsum[blockIdx.x] = s[255];
}

__global__ void k_scan_sums(int* __restrict__ bsum, int nb) {
  __shared__ int s[1024];
  int tid = threadIdx.x;
  int v = (tid < nb) ? bsum[tid] : 0;
  s[tid] = v;
  __syncthreads();
  for (int off = 1; off < 1024; off <<= 1) {
    int t = (tid >= off) ? s[tid - off] : 0;
    __syncthreads();
    s[tid] += t;
    __syncthreads();
  }
  if (tid < nb) bsum[tid] = s[tid] - v;
}

__global__ void k_scan_add(int* __restrict__ ptr, const int* __restrict__ bsum, int n, int total) {
  int i = blockIdx.x * 256 + threadIdx.x;
  if (i < n) ptr[i] += bsum[blockIdx.x];
  if (i == 0) ptr[n] = total;
}

__global__ void k_copy(int* __restrict__ dst, const int* __restrict__ src, int n) {
  int i = blockIdx.x * 256 + threadIdx.x;
  if (i < n) dst[i] = src[i];
}

__global__ void k_scatter3(const int* __restrict__ s0, const int* __restrict__ s1,
                           const int* __restrict__ s2, const int* __restrict__ d0,
                           const int* __restrict__ d1, const int* __restrict__ d2,
                           int* __restrict__ cursor, int* __restrict__ srcs_out) {
  int i = blockIdx.x * 256 + threadIdx.x;
  if (i >= 3 * NEDGE) return;
  int et = i / NEDGE, e = i - et * NEDGE;
  int d = (et == 0) ? d0[e] : (et == 1) ? d1[e] : d2[e];
  int sv = (et == 0) ? s0[e] : (et == 1) ? s1[e] : s2[e];
  int base = (et == 0) ? 0 : (et == 1) ? NC : 2 * NC;
  int p = atomicAdd(&cursor[base + d], 1);
  srcs_out[p] = sv;
}

// ---------------- per-layer B prep: 10 slabs, Kp=128 ----------------
// y=0: qW(l,0)  y=1..4: folds for x0 (k_et1,v_et1,k_et2,v_et2)
// y=5: qW(l,1)  y=6,7: folds for x1 (k_et0,v_et0)  y=8,9: aW(l,0), aW(l,1)
__global__ void prep_all(const float* __restrict__ kW, const float* __restrict__ kB,
                         const float* __restrict__ qW, const float* __restrict__ qB,
                         const float* __restrict__ vW, const float* __restrict__ vB,
                         const float* __restrict__ aW, const float* __restrict__ aB,
                         const float* __restrict__ arel, const float* __restrict__ mrel,
                         const float* __restrict__ prel, int l,
                         u16* __restrict__ Bth, u16* __restrict__ Btl,
                         float* __restrict__ biasOut) {
  int i = blockIdx.x;     // input dim 0..127
  int col = threadIdx.x;  // output col 0..127
  int y = blockIdx.y;
  size_t lw = (size_t)l * 2 * 16384, lb = (size_t)l * 2 * 128;
  size_t le = (size_t)l * 3 * 4096, lp = (size_t)l * 3 * 4;
  const float *W = nullptr, *bb = nullptr, *rel = nullptr, *pr = nullptr;
  float mscale = 1.0f;
  bool fold = false;
  switch (y) {
    case 0: W = qW + lw; bb = qB + lb; break;
    case 1: fold = true; W = kW + lw; bb = kB + lb; rel = arel + le + 4096; pr = prel + lp + 4; mscale = SCALE; break;
    case 2: fold = true; W = vW + lw; bb = vB + lb; rel = mrel + le + 4096; break;
    case 3: fold = true; W = kW + lw; bb = kB + lb; rel = arel + le + 8192; pr = prel + lp + 8; mscale = SCALE; break;
    case 4: fold = true; W = vW + lw; bb = vB + lb; rel = mrel + le + 8192; break;
    case 5: W = qW + lw + 16384; bb = qB + lb + 128; break;
    case 6: fold = true; W = kW + lw + 16384; bb = kB + lb + 128; rel = arel + le; pr = prel + lp; mscale = SCALE; break;
    case 7: fold = true; W = vW + lw + 16384; bb = vB + lb + 128; rel = mrel + le; break;
    case 8: W = aW + lw; bb = aB + lb; break;
    default: W = aW + lw + 16384; bb = aB + lb + 128; break;
  }
  int colOff = y * 128;
  if (!fold) {
    float v = W[i * 128 + col];
    u16 hi, lo;
    split2(v, hi, lo);
    Bth[(size_t)(colOff + col) * 128 + i] = hi;
    Btl[(size_t)(colOff + col) * 128 + i] = lo;
    if (i == 0) biasOut[colOff + col] = bb[col];
    return;
  }
  int h = col >> 5, f = col & 31;
  float m = (pr ? pr[h] : 1.0f) * mscale;
  float s = 0.0f;
  #pragma unroll
  for (int d = 0; d < 32; ++d)
    s += W[i * 128 + h * 32 + d] * rel[(h * 32 + d) * 32 + f];
  s *= m;
  u16 hi, lo;
  split2(s, hi, lo);
  Bth[(size_t)(colOff + col) * 128 + i] = hi;
  Btl[(size_t)(colOff + col) * 128 + i] = lo;
  if (i == 0) {
    float sb = 0.0f;
    #pragma unroll
    for (int d = 0; d < 32; ++d)
      sb += bb[h * 32 + d] * rel[(h * 32 + d) * 32 + f];
    biasOut[colOff + col] = sb * m;
  }
}

// ---------------- input weight split: y=0 context (K=300,Kp=320), y=1 question (768,768) ----
__global__ void split_in(const float* __restrict__ Wc, const float* __restrict__ bc,
                         const float* __restrict__ Wq, const float* __restrict__ bq,
                         u16* __restrict__ Bth, u16* __restrict__ Btl,
                         float* __restrict__ biasOut) {
  int n = blockIdx.x, y = blockIdx.y;
  const float* W = y ? Wq : Wc;
  const float* b = y ? bq : bc;
  int K = y ? FQ : FC, Kp = y ? 768 : 320;
  size_t boff = y ? (size_t)128 * 320 : 0;
  for (int k = threadIdx.x; k < Kp; k += 256) {
    float v = (k < K) ? W[(size_t)k * 128 + n] : 0.0f;
    u16 hi, lo;
    split2(v, hi, lo);
    Bth[boff + (size_t)n * Kp + k] = hi;
    Btl[boff + (size_t)n * Kp + k] = lo;
  }
  if (threadIdx.x == 0) biasOut[(y ? 128 : 0) + n] = b[n];
}

// ---------------- merged input projection GEMM: relu(x @ W + b) -> split pair ----------------
__global__ __launch_bounds__(256) void in_gemm(
    const float* __restrict__ xc, const float* __restrict__ xq,
    const u16* __restrict__ Bth, const u16* __restrict__ Btl,
    const float* __restrict__ biasBuf,
    u16* __restrict__ xh_all, u16* __restrict__ xl_all) {
  __shared__ u16 Ah[128][40];
  __shared__ u16 Al[128][40];
  __shared__ u16 Bh[128][40];
  __shared__ u16 Bl[128][40];
  int bid = blockIdx.x;
  const float* A32;
  int K, Kp, M, m0, rowbase, biasOff;
  size_t boff;
  if (bid < NB0) { A32 = xc; K = FC; Kp = 320; M = NC; m0 = bid * 128; rowbase = 0; boff = 0; biasOff = 0; }
  else { A32 = xq; K = FQ; Kp = 768; M = NQ; m0 = (bid - NB0) * 128; rowbase = NC; boff = (size_t)128 * 320; biasOff = 128; }
  const int tid = threadIdx.x, lane = tid & 63, wv = tid >> 6;
  const int l15 = lane & 15, g4 = lane >> 4, koff = g4 * 8;
  const int sr = tid >> 1, sc = (tid & 1) * 16;
  const bool rowok = (m0 + sr) < M;

  f32x4 acc[2][8];
  #pragma unroll
  for (int mi = 0; mi < 2; ++mi)
    #pragma unroll
    for (int ni = 0; ni < 8; ++ni) acc[mi][ni] = (f32x4){0.f, 0.f, 0.f, 0.f};

  for (int k0 = 0; k0 < K; k0 += 32) {
    float va[16];
    if (rowok && (k0 + 32 <= K)) {
      const float* ap = A32 + (size_t)(m0 + sr) * K + k0 + sc;
      #pragma unroll
      for (int j = 0; j < 4; ++j) {
        float4 f = *(const float4*)(ap + 4 * j);
        va[4 * j + 0] = f.x; va[4 * j + 1] = f.y; va[4 * j + 2] = f.z; va[4 * j + 3] = f.w;
      }
    } else {
      #pragma unroll
      for (int j = 0; j < 16; ++j) {
        int kc = k0 + sc + j;
        va[j] = (rowok && kc < K) ? A32[(size_t)(m0 + sr) * K + kc] : 0.0f;
      }
    }
    alignas(16) u16 hv[16], lv[16];
    #pragma unroll
    for (int j = 0; j < 16; ++j) split2(va[j], hv[j], lv[j]);
    *(uint4*)&Ah[sr][sc] = *(const uint4*)&hv[0];
    *(uint4*)&Ah[sr][sc + 8] = *(const uint4*)&hv[8];
    *(uint4*)&Al[sr][sc] = *(const uint4*)&lv[0];
    *(uint4*)&Al[sr][sc + 8] = *(const uint4*)&lv[8];
    {
      const u16* bp = Bth + boff + (size_t)sr * Kp + k0 + sc;
      *(uint4*)&Bh[sr][sc] = *(const uint4*)bp;
      *(uint4*)&Bh[sr][sc + 8] = *(const uint4*)(bp + 8);
      const u16* lp = Btl + boff + (size_t)sr * Kp + k0 + sc;
      *(uint4*)&Bl[sr][sc] = *(const uint4*)lp;
      *(uint4*)&Bl[sr][sc + 8] = *(const uint4*)(lp + 8);
    }
    __syncthreads();

    bf16x8 a_h[2], a_l[2];
    #pragma unroll
    for (int mi = 0; mi < 2; ++mi) {
      int row = wv * 32 + mi * 16 + l15;
      a_h[mi] = *(const bf16x8*)&Ah[row][koff];
      a_l[mi] = *(const bf16x8*)&Al[row][koff];
    }
    #pragma unroll
    for (int ni = 0; ni < 8; ++ni) {
      int col = ni * 16 + l15;
      bf16x8 b_h = *(const bf16x8*)&Bh[col][koff];
      bf16x8 b_l = *(const bf16x8*)&Bl[col][koff];
      #pragma unroll
      for (int mi = 0; mi < 2; ++mi) {
        acc[mi][ni] = __builtin_amdgcn_mfma_f32_16x16x32_bf16(a_h[mi], b_h, acc[mi][ni], 0, 0, 0);
        acc[mi][ni] = __builtin_amdgcn_mfma_f32_16x16x32_bf16(a_l[mi], b_h, acc[mi][ni], 0, 0, 0);
        acc[mi][ni] = __builtin_amdgcn_mfma_f32_16x16x32_bf16(a_h[mi], b_l, acc[mi][ni], 0, 0, 0);
      }
    }
    __syncthreads();
  }

  #pragma unroll
  for (int mi = 0; mi < 2; ++mi) {
    #pragma unroll
    for (int ni = 0; ni < 8; ++ni) {
      int colL = ni * 16 + l15;
      float bi = biasBuf[biasOff + colL];
      int rbase = m0 + wv * 32 + mi * 16 + g4 * 4;
      #pragma unroll
      for (int rr = 0; rr < 4; ++rr) {
        int row = rbase + rr;
        if (row >= M) continue;
        float o = fmaxf(acc[mi][ni][rr] + bi, 0.0f);
        u16 hh, ll;
        split2(o, hh, ll);
        xh_all[(size_t)(rowbase + row) * 128 + colL] = hh;
        xl_all[(size_t)(rowbase + row) * 128 + colL] = ll;
      }
    }
  }
}

// ---------------- merged q/kv projection GEMM (pre-split A, slab-routed C) ----------------
__global__ __launch_bounds__(256) void proj_all(
    const u16* __restrict__ xh_all, const u16* __restrict__ xl_all,
    const u16* __restrict__ Bth, const u16* __restrict__ Btl,
    const float* __restrict__ biasBuf,
    float* __restrict__ q_all, u16* __restrict__ kvA,
    u16* __restrict__ kvB1, u16* __restrict__ kvB2) {
  int bid = blockIdx.x, y = blockIdx.y;
  int nt = (bid < NB0) ? 0 : 1;
  if (nt == 1 && y >= 3) return;
  __shared__ u16 Ah[128][40];
  __shared__ u16 Al[128][40];
  __shared__ u16 Bh[128][40];
  __shared__ u16 Bl[128][40];
  int m0 = nt ? (bid - NB0) * 128 : bid * 128;
  int M = nt ? NQ : NC;
  int abase = nt ? NC : 0;
  int bslab = nt ? 5 + y : y;
  void* cp; int ld, cb, isb, crowbase;
  if (nt == 0) {
    switch (y) {
      case 0: cp = q_all; ld = 128; cb = 0; isb = 0; crowbase = 0; break;
      case 1: cp = kvB1; ld = 256; cb = 0; isb = 1; crowbase = 0; break;
      case 2: cp = kvB1; ld = 256; cb = 128; isb = 1; crowbase = 0; break;
      case 3: cp = kvB2; ld = 256; cb = 0; isb = 1; crowbase = 0; break;
      default: cp = kvB2; ld = 256; cb = 128; isb = 1; crowbase = 0; break;
    }
  } else {
    switch (y) {
      case 0: cp = q_all; ld = 128; cb = 0; isb = 0; crowbase = NC; break;
      case 1: cp = kvA; ld = 256; cb = 0; isb = 1; crowbase = 0; break;
      default: cp = kvA; ld = 256; cb = 128; isb = 1; crowbase = 0; break;
    }
  }
  const int tid = threadIdx.x, lane = tid & 63, wv = tid >> 6;
  const int l15 = lane & 15, g4 = lane >> 4, koff = g4 * 8;
  const int sr = tid >> 1, sc = (tid & 1) * 16;
  const bool rowok = (m0 + sr) < M;

  f32x4 acc[2][8];
  #pragma unroll
  for (int mi = 0; mi < 2; ++mi)
    #pragma unroll
    for (int ni = 0; ni < 8; ++ni) acc[mi][ni] = (f32x4){0.f, 0.f, 0.f, 0.f};

  for (int k0 = 0; k0 < 128; k0 += 32) {
    uint4 h0 = {0, 0, 0, 0}, h1 = {0, 0, 0, 0}, l0 = {0, 0, 0, 0}, l1 = {0, 0, 0, 0};
    if (rowok) {
      const u16* ap = xh_all + (size_t)(abase + m0 + sr) * 128 + k0 + sc;
      h0 = *(const uint4*)ap;
      h1 = *(const uint4*)(ap + 8);
      const u16* lp = xl_all + (size_t)(abase + m0 + sr) * 128 + k0 + sc;
      l0 = *(const uint4*)lp;
      l1 = *(const uint4*)(lp + 8);
    }
    *(uint4*)&Ah[sr][sc] = h0;
    *(uint4*)&Ah[sr][sc + 8] = h1;
    *(uint4*)&Al[sr][sc] = l0;
    *(uint4*)&Al[sr][sc + 8] = l1;
    {
      const u16* bp = Bth + (size_t)(bslab * 128 + sr) * 128 + k0 + sc;
      *(uint4*)&Bh[sr][sc] = *(const uint4*)bp;
      *(uint4*)&Bh[sr][sc + 8] = *(const uint4*)(bp + 8);
      const u16* lp = Btl + (size_t)(bslab * 128 + sr) * 128 + k0 + sc;
      *(uint4*)&Bl[sr][sc] = *(const uint4*)lp;
      *(uint4*)&Bl[sr][sc + 8] = *(const uint4*)(lp + 8);
    }
    __syncthreads();

    bf16x8 a_h[2], a_l[2];
    #pragma unroll
    for (int mi = 0; mi < 2; ++mi) {
      int row = wv * 32 + mi * 16 + l15;
      a_h[mi] = *(const bf16x8*)&Ah[row][koff];
      a_l[mi] = *(const bf16x8*)&Al[row][koff];
    }
    #pragma unroll
    for (int ni = 0; ni < 8; ++ni) {
      int col = ni * 16 + l15;
      bf16x8 b_h = *(const bf16x8*)&Bh[col][koff];
      bf16x8 b_l = *(const bf16x8*)&Bl[col][koff];
      #pragma unroll
      for (int mi = 0; mi < 2; ++mi) {
        acc[mi][ni] = __builtin_amdgcn_mfma_f32_16x16x32_bf16(a_h[mi], b_h, acc[mi][ni], 0, 0, 0);
        acc[mi][ni] = __builtin_amdgcn_mfma_f32_16x16x32_bf16(a_l[mi], b_h, acc[mi][ni], 0, 0, 0);
        acc[mi][ni] = __builtin_amdgcn_mfma_f32_16x16x32_bf16(a_h[mi], b_l, acc[mi][ni], 0, 0, 0);
      }
    }
    __syncthreads();
  }

  #pragma unroll
  for (int mi = 0; mi < 2; ++mi) {
    #pragma unroll
    for (int ni = 0; ni < 8; ++ni) {
      int colL = ni * 16 + l15;
      float bi = biasBuf[bslab * 128 + colL];
      int rbase = m0 + wv * 32 + mi * 16 + g4 * 4;
      #pragma unroll
      for (int rr = 0; rr < 4; ++rr) {
        int row = rbase + rr;
        if (row >= M) continue;
        float o = acc[mi][ni][rr] + bi;
        if (isb)
          ((u16*)cp)[(size_t)(crowbase + row) * ld + cb + colL] = bf16_rne(o);
        else
          ((float*)cp)[(size_t)(crowbase + row) * ld + cb + colL] = o;
      }
    }
  }
}

// ---------------- merged a-projection: gelu(agg) @ aW + skip-gate -> x pair ----------------
__global__ __launch_bounds__(256) void aproj_all(
    const float* __restrict__ agg_all,
    const u16* __restrict__ Bth, const u16* __restrict__ Btl,
    const float* __restrict__ biasBuf,
    u16* __restrict__ xh_all, u16* __restrict__ xl_all,
    const float* __restrict__ skip, int l) {
  __shared__ u16 Ah[128][40];
  __shared__ u16 Al[128][40];
  __shared__ u16 Bh[128][40];
  __shared__ u16 Bl[128][40];
  int bid = blockIdx.x;
  int nt = (bid < NB0) ? 0 : 1;
  int m0 = nt ? (bid - NB0) * 128 : bid * 128;
  int M = nt ? NQ : NC;
  int base = nt ? NC : 0;
  int bslab = 8 + nt;
  float g = 1.0f / (1.0f + __expf(-skip[l * 2 + nt]));
  const int tid = threadIdx.x, lane = tid & 63, wv = tid >> 6;
  const int l15 = lane & 15, g4 = lane >> 4, koff = g4 * 8;
  const int sr = tid >> 1, sc = (tid & 1) * 16;
  const bool rowok = (m0 + sr) < M;

  f32x4 acc[2][8];
  #pragma unroll
  for (int mi = 0; mi < 2; ++mi)
    #pragma unroll
    for (int ni = 0; ni < 8; ++ni) acc[mi][ni] = (f32x4){0.f, 0.f, 0.f, 0.f};

  for (int k0 = 0; k0 < 128; k0 += 32) {
    float va[16];
    if (rowok) {
      const float* ap = agg_all + (size_t)(base + m0 + sr) * 128 + k0 + sc;
      #pragma unroll
      for (int j = 0; j < 4; ++j) {
        float4 f = *(const float4*)(ap + 4 * j);
        va[4 * j + 0] = f.x; va[4 * j + 1] = f.y; va[4 * j + 2] = f.z; va[4 * j + 3] = f.w;
      }
    } else {
      #pragma unroll
      for (int j = 0; j < 16; ++j) va[j] = 0.0f;
    }
    alignas(16) u16 hv[16], lv[16];
    #pragma unroll
    for (int j = 0; j < 16; ++j) {
      float x = gelu_f(va[j]);
      split2(x, hv[j], lv[j]);
    }
    *(uint4*)&Ah[sr][sc] = *(const uint4*)&hv[0];
    *(uint4*)&Ah[sr][sc + 8] = *(const uint4*)&hv[8];
    *(uint4*)&Al[sr][sc] = *(const uint4*)&lv[0];
    *(uint4*)&Al[sr][sc + 8] = *(const uint4*)&lv[8];
    {
      const u16* bp = Bth + (size_t)(bslab * 128 + sr) * 128 + k0 + sc;
      *(uint4*)&Bh[sr][sc] = *(const uint4*)bp;
      *(uint4*)&Bh[sr][sc + 8] = *(const uint4*)(bp + 8);
      const u16* lp = Btl + (size_t)(bslab * 128 + sr) * 128 + k0 + sc;
      *(uint4*)&Bl[sr][sc] = *(const uint4*)lp;
      *(uint4*)&Bl[sr][sc + 8] = *(const uint4*)(lp + 8);
    }
    __syncthreads();

    bf16x8 a_h[2], a_l[2];
    #pragma unroll
    for (int mi = 0; mi < 2; ++mi) {
      int row = wv * 32 + mi * 16 + l15;
      a_h[mi] = *(const bf16x8*)&Ah[row][koff];
      a_l[mi] = *(const bf16x8*)&Al[row][koff];
    }
    #pragma unroll
    for (int ni = 0; ni < 8; ++ni) {
      int col = ni * 16 + l15;
      bf16x8 b_h = *(const bf16x8*)&Bh[col][koff];
      bf16x8 b_l = *(const bf16x8*)&Bl[col][koff];
      #pragma unroll
      for (int mi = 0; mi < 2; ++mi) {
        acc[mi][ni] = __builtin_amdgcn_mfma_f32_16x16x32_bf16(a_h[mi], b_h, acc[mi][ni], 0, 0, 0);
        acc[mi][ni] = __builtin_amdgcn_mfma_f32_16x16x32_bf16(a_l[mi], b_h, acc[mi][ni], 0, 0, 0);
        acc[mi][ni] = __builtin_amdgcn_mfma_f32_16x16x32_bf16(a_h[mi], b_l, acc[mi][ni], 0, 0, 0);
      }
    }
    __syncthreads();
  }

  #pragma unroll
  for (int mi = 0; mi < 2; ++mi) {
    #pragma unroll
    for (int ni = 0; ni < 8; ++ni) {
      int colL = ni * 16 + l15;
      float bi = biasBuf[bslab * 128 + colL];
      int rbase = m0 + wv * 32 + mi * 16 + g4 * 4;
      #pragma unroll
      for (int rr = 0; rr < 4; ++rr) {
        int row = rbase + rr;
        if (row >= M) continue;
        size_t idx = (size_t)(base + row) * 128 + colL;
        float xo = bf16_to_f(xh_all[idx]) + bf16_to_f(xl_all[idx]);
        float o = g * (acc[mi][ni][rr] + bi) + (1.0f - g) * xo;
        u16 hh, ll;
        split2(o, hh, ll);
        xh_all[idx] = hh;
        xl_all[idx] = ll;
      }
    }
  }
}

// ---------------- merged attention: one wave per dst node, direct exp2 softmax --------------
__device__ __forceinline__ void attn_seg(
    const u16* __restrict__ kv, const int* __restrict__ ptr, int idx,
    const int* __restrict__ srcs, const float4& q4, int lane, float4& total) {
  int start = ptr[idx], end = ptr[idx + 1];
  if (start == end) return;
  float sum = 0.0f;
  float4 acc = make_float4(0.f, 0.f, 0.f, 0.f);
  for (int e = start; e < end; e += 4) {
    int nb = end - e;
    nb = nb > 4 ? 4 : nb;
    int sA[4];
    #pragma unroll
    for (int j = 0; j < 4; ++j) {
      int ee = e + j;
      ee = (ee < end - 1) ? ee : (end - 1);
      sA[j] = srcs[ee];
    }
    float4 r[4];
    #pragma unroll
    for (int j = 0; j < 4; ++j) {
      uint2 u = *(const uint2*)&kv[(size_t)sA[j] * 256 + lane * 4];
      r[j].x = bf16_to_f((u16)(u.x & 0xffffu));
      r[j].y = bf16_to_f((u16)(u.x >> 16));
      r[j].z = bf16_to_f((u16)(u.y & 0xffffu));
      r[j].w = bf16_to_f((u16)(u.y >> 16));
    }
    #pragma unroll
    for (int j = 0; j < 4; ++j) {
      if (j < nb) {  // wave-uniform
        float p = q4.x * r[j].x + q4.y * r[j].y + q4.z * r[j].z + q4.w * r[j].w;
        p += __shfl_xor(p, 1);
        p += __shfl_xor(p, 2);
        p += __shfl_xor(p, 4);
        p = fminf(p, 100.0f);          // overflow guard; logits are O(1) in log2 domain
        float w = exp2f(p);            // q pre-scaled by log2(e)
        float wB = __shfl(w, lane & 31);
        sum += wB;
        acc.x += wB * r[j].x;
        acc.y += wB * r[j].y;
        acc.z += wB * r[j].z;
        acc.w += wB * r[j].w;
      }
    }
  }
  float inv = 1.0f / (sum + 1e-16f);   // per-lane sum already correct on v-lanes
  total.x += acc.x * inv;
  total.y += acc.y * inv;
  total.z += acc.z * inv;
  total.w += acc.w * inv;
}

__global__ __launch_bounds__(256) void attn_all(
    const float* __restrict__ q_all, const u16* __restrict__ kvA,
    const u16* __restrict__ kvB1, const u16* __restrict__ kvB2,
    const int* __restrict__ ptr_all, const int* __restrict__ srcs_all,
    float* __restrict__ agg_all) {
  int wave = threadIdx.x >> 6, lane = threadIdx.x & 63;
  int node = blockIdx.x * 4 + wave;
  if (node >= NTOT2) return;
  float4 q4 = make_float4(0.f, 0.f, 0.f, 0.f);
  if (lane < 32) {
    q4 = *(const float4*)&q_all[(size_t)node * 128 + lane * 4];
    q4.x *= LOG2E; q4.y *= LOG2E; q4.z *= LOG2E; q4.w *= LOG2E;
  }
  float4 total = make_float4(0.f, 0.f, 0.f, 0.f);
  if (node < NC) {
    attn_seg(kvA, ptr_all, node, srcs_all, q4, lane, total);
    attn_seg(kvB1, ptr_all + NC, node, srcs_all, q4, lane, total);
  } else {
    attn_seg(kvB2, ptr_all + 2 * NC, node - NC, srcs_all, q4, lane, total);
  }
  if (lane >= 32)
    *(float4*)&agg_all[(size_t)node * 128 + (lane - 32) * 4] = total;
}

// ---------------- final projection ----------------
__global__ __launch_bounds__(256) void gemm_out(const u16* __restrict__ Xh,
                                                const u16* __restrict__ Xl,
                                                const float* __restrict__ W,
                                                const float* __restrict__ b,
                                                float* __restrict__ out, int M) {
  __shared__ float Ws[1024];
  __shared__ float As[32][129];
  int tid = threadIdx.x;
  int m0 = blockIdx.x * 32;
  *(float4*)&Ws[tid * 4] = *(const float4*)&W[tid * 4];
  {
    int r = tid >> 3;
    int c0 = (tid & 7) * 16;
    if (m0 + r < M) {
      const u16* hp = Xh + (size_t)(m0 + r) * 128 + c0;
      const u16* lp = Xl + (size_t)(m0 + r) * 128 + c0;
      #pragma unroll
      for (int j = 0; j < 16; ++j) As[r][c0 + j] = bf16_to_f(hp[j]) + bf16_to_f(lp[j]);
    } else {
      #pragma unroll
      for (int j = 0; j < 16; ++j) As[r][c0 + j] = 0.0f;
    }
  }
  __syncthreads();
  int r = tid >> 3, c = tid & 7;
  float sum = b[c];
  #pragma unroll 16
  for (int k = 0; k < 128; ++k) sum = fmaf(As[r][k], Ws[k * 8 + c], sum);
  if (m0 + r < M) out[(size_t)(m0 + r) * 8 + c] = sum;
}

// ---------------- host orchestration ----------------
static inline size_t align256(size_t x) { return (x + 255) & ~(size_t)255; }

extern "C" void kernel_launch(void* const* d_in, const int* in_sizes, int n_in,
                              void* d_out, int out_size, void* d_ws, size_t ws_size,
                              hipStream_t stream) {
  const float* x_context = (const float*)d_in[0];
  const float* x_question = (const float*)d_in[1];
  const int* src_q2c = (const int*)d_in[2];
  const int* dst_q2c = (const int*)d_in[3];
  const int* src_c2c = (const int*)d_in[4];
  const int* dst_c2c = (const int*)d_in[5];
  const int* src_c2q = (const int*)d_in[6];
  const int* dst_c2q = (const int*)d_in[7];
  const float* inWc = (const float*)d_in[8];
  const float* inbc = (const float*)d_in[9];
  const float* inWq = (const float*)d_in[10];
  const float* inbq = (const float*)d_in[11];
  const float* kW = (const float*)d_in[12];
  const float* kB = (const float*)d_in[13];
  const float* qW = (const float*)d_in[14];
  const float* qB = (const float*)d_in[15];
  const float* vW = (const float*)d_in[16];
  const float* vB = (const float*)d_in[17];
  const float* aW = (const float*)d_in[18];
  const float* aB = (const float*)d_in[19];
  const float* skip = (const float*)d_in[20];
  const float* arel = (const float*)d_in[21];
  const float* mrel = (const float*)d_in[22];
  const float* prel = (const float*)d_in[23];
  const float* outW = (const float*)d_in[24];
  const float* outb = (const float*)d_in[25];

  char* base = (char*)d_ws;
  size_t off = 0;
  auto carve = [&](size_t bytes) -> void* {
    void* p = base + off;
    off = align256(off + bytes);
    return p;
  };
  u16* xh_all = (u16*)carve((size_t)NTOT2 * 128 * 2);
  u16* xl_all = (u16*)carve((size_t)NTOT2 * 128 * 2);
  float* q_all = (float*)carve((size_t)NTOT2 * 128 * 4);
  u16* kvA = (u16*)carve((size_t)NQ * 256 * 2);
  u16* kvB1 = (u16*)carve((size_t)NC * 256 * 2);
  u16* kvB2 = (u16*)carve((size_t)NC * 256 * 2);
  float* agg_all = (float*)carve((size_t)NTOT2 * 128 * 4);
  u16* Bth = (u16*)carve((size_t)1280 * 128 * 2);
  u16* Btl = (u16*)carve((size_t)1280 * 128 * 2);
  float* biasBuf = (float*)carve(1280 * 4);
  int* ptr_all = (int*)carve((size_t)(NTOT + 1) * 4);
  int* srcs_all = (int*)carve((size_t)3 * NEDGE * 4);
  int* counts = (int*)carve((size_t)NTOT * 4);
  int* cursor = (int*)carve((size_t)NTOT * 4);
  int* blksums = (int*)carve(2048 * 4);

  // ---- fused CSR build ----
  {
    int nb = (NTOT + 255) / 256;
    hipMemsetAsync(counts, 0, (size_t)NTOT * 4, stream);
    k_count3<<<(3 * NEDGE + 255) / 256, 256, 0, stream>>>(dst_q2c, dst_c2c, dst_c2q, counts);
    k_scan_block<<<nb, 256, 0, stream>>>(counts, ptr_all, blksums, NTOT);
    k_scan_sums<<<1, 1024, 0, stream>>>(blksums, nb);
    k_scan_add<<<nb, 256, 0, stream>>>(ptr_all, blksums, NTOT, 3 * NEDGE);
    k_copy<<<nb, 256, 0, stream>>>(cursor, ptr_all, NTOT);
    k_scatter3<<<(3 * NEDGE + 255) / 256, 256, 0, stream>>>(
        src_q2c, src_c2c, src_c2q, dst_q2c, dst_c2c, dst_c2q, cursor, srcs_all);
  }

  // ---- merged input projections ----
  split_in<<<dim3(128, 2), 256, 0, stream>>>(inWc, inbc, inWq, inbq, Bth, Btl, biasBuf);
  in_gemm<<<NBALL, 256, 0, stream>>>(x_context, x_question, Bth, Btl, biasBuf, xh_all, xl_all);

  for (int l = 0; l < 2; ++l) {
    prep_all<<<dim3(128, 10), 128, 0, stream>>>(kW, kB, qW, qB, vW, vB, aW, aB,
                                                arel, mrel, prel, l, Bth, Btl, biasBuf);
    proj_all<<<dim3(NBALL, 5), 256, 0, stream>>>(xh_all, xl_all, Bth, Btl, biasBuf,
                                                 q_all, kvA, kvB1, kvB2);
    attn_all<<<(NTOT2 + 3) / 4, 256, 0, stream>>>(q_all, kvA, kvB1, kvB2,
                                                  ptr_all, srcs_all, agg_all);
    aproj_all<<<NBALL, 256, 0, stream>>>(agg_all, Bth, Btl, biasBuf,
                                         xh_all, xl_all, skip, l);
  }

  gemm_out<<<(NC + 31) / 32, 256, 0, stream>>>(xh_all, xl_all, outW, outb, (float*)d_out, NC);
}

// Round 7
// 889.975 us; speedup vs baseline: 1.7381x; 1.1022x over previous
//
#include <hip/hip_runtime.h>

constexpr int NC = 100000;
constexpr int NQ = 20000;
constexpr int FC = 300;
constexpr int FQ = 768;
constexpr int NEDGE = 400000;
constexpr int NTOT = NC + NC + NQ;   // concatenated dst segments: et0 | et1 | et2
constexpr int NTOT2 = NC + NQ;       // all nodes (context then question)
constexpr int NB0 = (NC + 127) / 128;  // 782
constexpr int NB1 = (NQ + 127) / 128;  // 157
constexpr int NBALL = NB0 + NB1;       // 939
constexpr float SCALE = 0.17677669529663687f;  // 1/sqrt(32)
constexpr float LOG2E = 1.4426950408889634f;

typedef __attribute__((ext_vector_type(8))) short bf16x8;
typedef __attribute__((ext_vector_type(4))) float f32x4;
typedef unsigned short u16;

__device__ __forceinline__ float gelu_f(float x) {
  return 0.5f * x * (1.0f + erff(x * 0.7071067811865476f));
}
__device__ __forceinline__ u16 bf16_rne(float x) {
  unsigned u = __float_as_uint(x);
  unsigned r = u + 0x7fffu + ((u >> 16) & 1u);
  return (u16)(r >> 16);
}
__device__ __forceinline__ float bf16_to_f(u16 h) {
  return __uint_as_float(((unsigned)h) << 16);
}
__device__ __forceinline__ void split2(float x, u16& hi, u16& lo) {
  hi = bf16_rne(x);
  lo = bf16_rne(x - bf16_to_f(hi));
}

// ---------------- fused CSR build over 3 edge types ----------------
__global__ void k_count3(const int* __restrict__ d0, const int* __restrict__ d1,
                         const int* __restrict__ d2, int* __restrict__ counts) {
  int i = blockIdx.x * 256 + threadIdx.x;
  if (i >= 3 * NEDGE) return;
  int et = i / NEDGE, e = i - et * NEDGE;
  int d = (et == 0) ? d0[e] : (et == 1) ? d1[e] : d2[e];
  int base = (et == 0) ? 0 : (et == 1) ? NC : 2 * NC;
  atomicAdd(&counts[base + d], 1);
}

__global__ void k_scan_block(const int* __restrict__ in, int* __restrict__ out,
                             int* __restrict__ bsum, int n) {
  __shared__ int s[256];
  int tid = threadIdx.x;
  int i = blockIdx.x * 256 + tid;
  int v = (i < n) ? in[i] : 0;
  s[tid] = v;
  __syncthreads();
  for (int off = 1; off < 256; off <<= 1) {
    int t = (tid >= off) ? s[tid - off] : 0;
    __syncthreads();
    s[tid] += t;
    __syncthreads();
  }
  if (i < n) out[i] = s[tid] - v;
  if (tid == 255) bsum[blockIdx.x] = s[255];
}

__global__ void k_scan_sums(int* __restrict__ bsum, int nb) {
  __shared__ int s[1024];
  int tid = threadIdx.x;
  int v = (tid < nb) ? bsum[tid] : 0;
  s[tid] = v;
  __syncthreads();
  for (int off = 1; off < 1024; off <<= 1) {
    int t = (tid >= off) ? s[tid - off] : 0;
    __syncthreads();
    s[tid] += t;
    __syncthreads();
  }
  if (tid < nb) bsum[tid] = s[tid] - v;
}

__global__ void k_scan_add(int* __restrict__ ptr, const int* __restrict__ bsum, int n, int total) {
  int i = blockIdx.x * 256 + threadIdx.x;
  if (i < n) ptr[i] += bsum[blockIdx.x];
  if (i == 0) ptr[n] = total;
}

__global__ void k_copy(int* __restrict__ dst, const int* __restrict__ src, int n) {
  int i = blockIdx.x * 256 + threadIdx.x;
  if (i < n) dst[i] = src[i];
}

__global__ void k_scatter3(const int* __restrict__ s0, const int* __restrict__ s1,
                           const int* __restrict__ s2, const int* __restrict__ d0,
                           const int* __restrict__ d1, const int* __restrict__ d2,
                           int* __restrict__ cursor, int* __restrict__ srcs_out) {
  int i = blockIdx.x * 256 + threadIdx.x;
  if (i >= 3 * NEDGE) return;
  int et = i / NEDGE, e = i - et * NEDGE;
  int d = (et == 0) ? d0[e] : (et == 1) ? d1[e] : d2[e];
  int sv = (et == 0) ? s0[e] : (et == 1) ? s1[e] : s2[e];
  int base = (et == 0) ? 0 : (et == 1) ? NC : 2 * NC;
  int p = atomicAdd(&cursor[base + d], 1);
  srcs_out[p] = sv;
}

// ---------------- per-layer B prep: 10 slabs, Kp=128 ----------------
__global__ void prep_all(const float* __restrict__ kW, const float* __restrict__ kB,
                         const float* __restrict__ qW, const float* __restrict__ qB,
                         const float* __restrict__ vW, const float* __restrict__ vB,
                         const float* __restrict__ aW, const float* __restrict__ aB,
                         const float* __restrict__ arel, const float* __restrict__ mrel,
                         const float* __restrict__ prel, int l,
                         u16* __restrict__ Bth, u16* __restrict__ Btl,
                         float* __restrict__ biasOut) {
  int i = blockIdx.x;     // input dim 0..127
  int col = threadIdx.x;  // output col 0..127
  int y = blockIdx.y;
  size_t lw = (size_t)l * 2 * 16384, lb = (size_t)l * 2 * 128;
  size_t le = (size_t)l * 3 * 4096, lp = (size_t)l * 3 * 4;
  const float *W = nullptr, *bb = nullptr, *rel = nullptr, *pr = nullptr;
  float mscale = 1.0f;
  bool fold = false;
  switch (y) {
    case 0: W = qW + lw; bb = qB + lb; break;
    case 1: fold = true; W = kW + lw; bb = kB + lb; rel = arel + le + 4096; pr = prel + lp + 4; mscale = SCALE; break;
    case 2: fold = true; W = vW + lw; bb = vB + lb; rel = mrel + le + 4096; break;
    case 3: fold = true; W = kW + lw; bb = kB + lb; rel = arel + le + 8192; pr = prel + lp + 8; mscale = SCALE; break;
    case 4: fold = true; W = vW + lw; bb = vB + lb; rel = mrel + le + 8192; break;
    case 5: W = qW + lw + 16384; bb = qB + lb + 128; break;
    case 6: fold = true; W = kW + lw + 16384; bb = kB + lb + 128; rel = arel + le; pr = prel + lp; mscale = SCALE; break;
    case 7: fold = true; W = vW + lw + 16384; bb = vB + lb + 128; rel = mrel + le; break;
    case 8: W = aW + lw; bb = aB + lb; break;
    default: W = aW + lw + 16384; bb = aB + lb + 128; break;
  }
  int colOff = y * 128;
  if (!fold) {
    float v = W[i * 128 + col];
    u16 hi, lo;
    split2(v, hi, lo);
    Bth[(size_t)(colOff + col) * 128 + i] = hi;
    Btl[(size_t)(colOff + col) * 128 + i] = lo;
    if (i == 0) biasOut[colOff + col] = bb[col];
    return;
  }
  int h = col >> 5, f = col & 31;
  float m = (pr ? pr[h] : 1.0f) * mscale;
  float s = 0.0f;
  #pragma unroll
  for (int d = 0; d < 32; ++d)
    s += W[i * 128 + h * 32 + d] * rel[(h * 32 + d) * 32 + f];
  s *= m;
  u16 hi, lo;
  split2(s, hi, lo);
  Bth[(size_t)(colOff + col) * 128 + i] = hi;
  Btl[(size_t)(colOff + col) * 128 + i] = lo;
  if (i == 0) {
    float sb = 0.0f;
    #pragma unroll
    for (int d = 0; d < 32; ++d)
      sb += bb[h * 32 + d] * rel[(h * 32 + d) * 32 + f];
    biasOut[colOff + col] = sb * m;
  }
}

// ---------------- input weight split: y=0 context (K=300,Kp=320), y=1 question (768,768) ----
__global__ void split_in(const float* __restrict__ Wc, const float* __restrict__ bc,
                         const float* __restrict__ Wq, const float* __restrict__ bq,
                         u16* __restrict__ Bth, u16* __restrict__ Btl,
                         float* __restrict__ biasOut) {
  int n = blockIdx.x, y = blockIdx.y;
  const float* W = y ? Wq : Wc;
  const float* b = y ? bq : bc;
  int K = y ? FQ : FC, Kp = y ? 768 : 320;
  size_t boff = y ? (size_t)128 * 320 : 0;
  for (int k = threadIdx.x; k < Kp; k += 256) {
    float v = (k < K) ? W[(size_t)k * 128 + n] : 0.0f;
    u16 hi, lo;
    split2(v, hi, lo);
    Bth[boff + (size_t)n * Kp + k] = hi;
    Btl[boff + (size_t)n * Kp + k] = lo;
  }
  if (threadIdx.x == 0) biasOut[(y ? 128 : 0) + n] = b[n];
}

// ---------------- merged input projection GEMM: relu(x @ W + b) -> split pair (3-term) ------
__global__ __launch_bounds__(256) void in_gemm(
    const float* __restrict__ xc, const float* __restrict__ xq,
    const u16* __restrict__ Bth, const u16* __restrict__ Btl,
    const float* __restrict__ biasBuf,
    u16* __restrict__ xh_all, u16* __restrict__ xl_all) {
  __shared__ u16 Ah[128][40];
  __shared__ u16 Al[128][40];
  __shared__ u16 Bh[128][40];
  __shared__ u16 Bl[128][40];
  int bid = blockIdx.x;
  const float* A32;
  int K, Kp, M, m0, rowbase, biasOff;
  size_t boff;
  if (bid < NB0) { A32 = xc; K = FC; Kp = 320; M = NC; m0 = bid * 128; rowbase = 0; boff = 0; biasOff = 0; }
  else { A32 = xq; K = FQ; Kp = 768; M = NQ; m0 = (bid - NB0) * 128; rowbase = NC; boff = (size_t)128 * 320; biasOff = 128; }
  const int tid = threadIdx.x, lane = tid & 63, wv = tid >> 6;
  const int l15 = lane & 15, g4 = lane >> 4, koff = g4 * 8;
  const int sr = tid >> 1, sc = (tid & 1) * 16;
  const bool rowok = (m0 + sr) < M;

  f32x4 acc[2][8];
  #pragma unroll
  for (int mi = 0; mi < 2; ++mi)
    #pragma unroll
    for (int ni = 0; ni < 8; ++ni) acc[mi][ni] = (f32x4){0.f, 0.f, 0.f, 0.f};

  for (int k0 = 0; k0 < K; k0 += 32) {
    float va[16];
    if (rowok && (k0 + 32 <= K)) {
      const float* ap = A32 + (size_t)(m0 + sr) * K + k0 + sc;
      #pragma unroll
      for (int j = 0; j < 4; ++j) {
        float4 f = *(const float4*)(ap + 4 * j);
        va[4 * j + 0] = f.x; va[4 * j + 1] = f.y; va[4 * j + 2] = f.z; va[4 * j + 3] = f.w;
      }
    } else {
      #pragma unroll
      for (int j = 0; j < 16; ++j) {
        int kc = k0 + sc + j;
        va[j] = (rowok && kc < K) ? A32[(size_t)(m0 + sr) * K + kc] : 0.0f;
      }
    }
    alignas(16) u16 hv[16], lv[16];
    #pragma unroll
    for (int j = 0; j < 16; ++j) split2(va[j], hv[j], lv[j]);
    *(uint4*)&Ah[sr][sc] = *(const uint4*)&hv[0];
    *(uint4*)&Ah[sr][sc + 8] = *(const uint4*)&hv[8];
    *(uint4*)&Al[sr][sc] = *(const uint4*)&lv[0];
    *(uint4*)&Al[sr][sc + 8] = *(const uint4*)&lv[8];
    {
      const u16* bp = Bth + boff + (size_t)sr * Kp + k0 + sc;
      *(uint4*)&Bh[sr][sc] = *(const uint4*)bp;
      *(uint4*)&Bh[sr][sc + 8] = *(const uint4*)(bp + 8);
      const u16* lp = Btl + boff + (size_t)sr * Kp + k0 + sc;
      *(uint4*)&Bl[sr][sc] = *(const uint4*)lp;
      *(uint4*)&Bl[sr][sc + 8] = *(const uint4*)(lp + 8);
    }
    __syncthreads();

    bf16x8 a_h[2], a_l[2];
    #pragma unroll
    for (int mi = 0; mi < 2; ++mi) {
      int row = wv * 32 + mi * 16 + l15;
      a_h[mi] = *(const bf16x8*)&Ah[row][koff];
      a_l[mi] = *(const bf16x8*)&Al[row][koff];
    }
    #pragma unroll
    for (int ni = 0; ni < 8; ++ni) {
      int col = ni * 16 + l15;
      bf16x8 b_h = *(const bf16x8*)&Bh[col][koff];
      bf16x8 b_l = *(const bf16x8*)&Bl[col][koff];
      #pragma unroll
      for (int mi = 0; mi < 2; ++mi) {
        acc[mi][ni] = __builtin_amdgcn_mfma_f32_16x16x32_bf16(a_h[mi], b_h, acc[mi][ni], 0, 0, 0);
        acc[mi][ni] = __builtin_amdgcn_mfma_f32_16x16x32_bf16(a_l[mi], b_h, acc[mi][ni], 0, 0, 0);
        acc[mi][ni] = __builtin_amdgcn_mfma_f32_16x16x32_bf16(a_h[mi], b_l, acc[mi][ni], 0, 0, 0);
      }
    }
    __syncthreads();
  }

  #pragma unroll
  for (int mi = 0; mi < 2; ++mi) {
    #pragma unroll
    for (int ni = 0; ni < 8; ++ni) {
      int colL = ni * 16 + l15;
      float bi = biasBuf[biasOff + colL];
      int rbase = m0 + wv * 32 + mi * 16 + g4 * 4;
      #pragma unroll
      for (int rr = 0; rr < 4; ++rr) {
        int row = rbase + rr;
        if (row >= M) continue;
        float o = fmaxf(acc[mi][ni][rr] + bi, 0.0f);
        u16 hh, ll;
        split2(o, hh, ll);
        xh_all[(size_t)(rowbase + row) * 128 + colL] = hh;
        xl_all[(size_t)(rowbase + row) * 128 + colL] = ll;
      }
    }
  }
}

// ---------------- merged q/kv projection GEMM: 1-term bf16 (xh @ Bh), slab-routed C ----------
__global__ __launch_bounds__(256) void proj_all(
    const u16* __restrict__ xh_all, const u16* __restrict__ xl_all,
    const u16* __restrict__ Bth, const u16* __restrict__ Btl,
    const float* __restrict__ biasBuf,
    float* __restrict__ q_all, u16* __restrict__ kvA,
    u16* __restrict__ kvB1, u16* __restrict__ kvB2) {
  int bid = blockIdx.x, y = blockIdx.y;
  int nt = (bid < NB0) ? 0 : 1;
  if (nt == 1 && y >= 3) return;
  __shared__ u16 Ah[128][40];
  __shared__ u16 Bh[128][40];
  int m0 = nt ? (bid - NB0) * 128 : bid * 128;
  int M = nt ? NQ : NC;
  int abase = nt ? NC : 0;
  int bslab = nt ? 5 + y : y;
  void* cp; int ld, cb, isb, crowbase;
  if (nt == 0) {
    switch (y) {
      case 0: cp = q_all; ld = 128; cb = 0; isb = 0; crowbase = 0; break;
      case 1: cp = kvB1; ld = 256; cb = 0; isb = 1; crowbase = 0; break;
      case 2: cp = kvB1; ld = 256; cb = 128; isb = 1; crowbase = 0; break;
      case 3: cp = kvB2; ld = 256; cb = 0; isb = 1; crowbase = 0; break;
      default: cp = kvB2; ld = 256; cb = 128; isb = 1; crowbase = 0; break;
    }
  } else {
    switch (y) {
      case 0: cp = q_all; ld = 128; cb = 0; isb = 0; crowbase = NC; break;
      case 1: cp = kvA; ld = 256; cb = 0; isb = 1; crowbase = 0; break;
      default: cp = kvA; ld = 256; cb = 128; isb = 1; crowbase = 0; break;
    }
  }
  const int tid = threadIdx.x, lane = tid & 63, wv = tid >> 6;
  const int l15 = lane & 15, g4 = lane >> 4, koff = g4 * 8;
  const int sr = tid >> 1, sc = (tid & 1) * 16;
  const bool rowok = (m0 + sr) < M;

  f32x4 acc[2][8];
  #pragma unroll
  for (int mi = 0; mi < 2; ++mi)
    #pragma unroll
    for (int ni = 0; ni < 8; ++ni) acc[mi][ni] = (f32x4){0.f, 0.f, 0.f, 0.f};

  for (int k0 = 0; k0 < 128; k0 += 32) {
    uint4 h0 = {0, 0, 0, 0}, h1 = {0, 0, 0, 0};
    if (rowok) {
      const u16* ap = xh_all + (size_t)(abase + m0 + sr) * 128 + k0 + sc;
      h0 = *(const uint4*)ap;
      h1 = *(const uint4*)(ap + 8);
    }
    *(uint4*)&Ah[sr][sc] = h0;
    *(uint4*)&Ah[sr][sc + 8] = h1;
    {
      const u16* bp = Bth + (size_t)(bslab * 128 + sr) * 128 + k0 + sc;
      *(uint4*)&Bh[sr][sc] = *(const uint4*)bp;
      *(uint4*)&Bh[sr][sc + 8] = *(const uint4*)(bp + 8);
    }
    __syncthreads();

    bf16x8 a_h[2];
    #pragma unroll
    for (int mi = 0; mi < 2; ++mi) {
      int row = wv * 32 + mi * 16 + l15;
      a_h[mi] = *(const bf16x8*)&Ah[row][koff];
    }
    #pragma unroll
    for (int ni = 0; ni < 8; ++ni) {
      int col = ni * 16 + l15;
      bf16x8 b_h = *(const bf16x8*)&Bh[col][koff];
      #pragma unroll
      for (int mi = 0; mi < 2; ++mi)
        acc[mi][ni] = __builtin_amdgcn_mfma_f32_16x16x32_bf16(a_h[mi], b_h, acc[mi][ni], 0, 0, 0);
    }
    __syncthreads();
  }

  #pragma unroll
  for (int mi = 0; mi < 2; ++mi) {
    #pragma unroll
    for (int ni = 0; ni < 8; ++ni) {
      int colL = ni * 16 + l15;
      float bi = biasBuf[bslab * 128 + colL];
      int rbase = m0 + wv * 32 + mi * 16 + g4 * 4;
      #pragma unroll
      for (int rr = 0; rr < 4; ++rr) {
        int row = rbase + rr;
        if (row >= M) continue;
        float o = acc[mi][ni][rr] + bi;
        if (isb)
          ((u16*)cp)[(size_t)(crowbase + row) * ld + cb + colL] = bf16_rne(o);
        else
          ((float*)cp)[(size_t)(crowbase + row) * ld + cb + colL] = o;
      }
    }
  }
}

// ---------------- merged a-projection: gelu(agg) @ aW + skip-gate -> x pair (3-term) --------
__global__ __launch_bounds__(256) void aproj_all(
    const float* __restrict__ agg_all,
    const u16* __restrict__ Bth, const u16* __restrict__ Btl,
    const float* __restrict__ biasBuf,
    u16* __restrict__ xh_all, u16* __restrict__ xl_all,
    const float* __restrict__ skip, int l) {
  __shared__ u16 Ah[128][40];
  __shared__ u16 Al[128][40];
  __shared__ u16 Bh[128][40];
  __shared__ u16 Bl[128][40];
  int bid = blockIdx.x;
  int nt = (bid < NB0) ? 0 : 1;
  int m0 = nt ? (bid - NB0) * 128 : bid * 128;
  int M = nt ? NQ : NC;
  int base = nt ? NC : 0;
  int bslab = 8 + nt;
  float g = 1.0f / (1.0f + __expf(-skip[l * 2 + nt]));
  const int tid = threadIdx.x, lane = tid & 63, wv = tid >> 6;
  const int l15 = lane & 15, g4 = lane >> 4, koff = g4 * 8;
  const int sr = tid >> 1, sc = (tid & 1) * 16;
  const bool rowok = (m0 + sr) < M;

  f32x4 acc[2][8];
  #pragma unroll
  for (int mi = 0; mi < 2; ++mi)
    #pragma unroll
    for (int ni = 0; ni < 8; ++ni) acc[mi][ni] = (f32x4){0.f, 0.f, 0.f, 0.f};

  for (int k0 = 0; k0 < 128; k0 += 32) {
    float va[16];
    if (rowok) {
      const float* ap = agg_all + (size_t)(base + m0 + sr) * 128 + k0 + sc;
      #pragma unroll
      for (int j = 0; j < 4; ++j) {
        float4 f = *(const float4*)(ap + 4 * j);
        va[4 * j + 0] = f.x; va[4 * j + 1] = f.y; va[4 * j + 2] = f.z; va[4 * j + 3] = f.w;
      }
    } else {
      #pragma unroll
      for (int j = 0; j < 16; ++j) va[j] = 0.0f;
    }
    alignas(16) u16 hv[16], lv[16];
    #pragma unroll
    for (int j = 0; j < 16; ++j) {
      float x = gelu_f(va[j]);
      split2(x, hv[j], lv[j]);
    }
    *(uint4*)&Ah[sr][sc] = *(const uint4*)&hv[0];
    *(uint4*)&Ah[sr][sc + 8] = *(const uint4*)&hv[8];
    *(uint4*)&Al[sr][sc] = *(const uint4*)&lv[0];
    *(uint4*)&Al[sr][sc + 8] = *(const uint4*)&lv[8];
    {
      const u16* bp = Bth + (size_t)(bslab * 128 + sr) * 128 + k0 + sc;
      *(uint4*)&Bh[sr][sc] = *(const uint4*)bp;
      *(uint4*)&Bh[sr][sc + 8] = *(const uint4*)(bp + 8);
      const u16* lp = Btl + (size_t)(bslab * 128 + sr) * 128 + k0 + sc;
      *(uint4*)&Bl[sr][sc] = *(const uint4*)lp;
      *(uint4*)&Bl[sr][sc + 8] = *(const uint4*)(lp + 8);
    }
    __syncthreads();

    bf16x8 a_h[2], a_l[2];
    #pragma unroll
    for (int mi = 0; mi < 2; ++mi) {
      int row = wv * 32 + mi * 16 + l15;
      a_h[mi] = *(const bf16x8*)&Ah[row][koff];
      a_l[mi] = *(const bf16x8*)&Al[row][koff];
    }
    #pragma unroll
    for (int ni = 0; ni < 8; ++ni) {
      int col = ni * 16 + l15;
      bf16x8 b_h = *(const bf16x8*)&Bh[col][koff];
      bf16x8 b_l = *(const bf16x8*)&Bl[col][koff];
      #pragma unroll
      for (int mi = 0; mi < 2; ++mi) {
        acc[mi][ni] = __builtin_amdgcn_mfma_f32_16x16x32_bf16(a_h[mi], b_h, acc[mi][ni], 0, 0, 0);
        acc[mi][ni] = __builtin_amdgcn_mfma_f32_16x16x32_bf16(a_l[mi], b_h, acc[mi][ni], 0, 0, 0);
        acc[mi][ni] = __builtin_amdgcn_mfma_f32_16x16x32_bf16(a_h[mi], b_l, acc[mi][ni], 0, 0, 0);
      }
    }
    __syncthreads();
  }

  #pragma unroll
  for (int mi = 0; mi < 2; ++mi) {
    #pragma unroll
    for (int ni = 0; ni < 8; ++ni) {
      int colL = ni * 16 + l15;
      float bi = biasBuf[bslab * 128 + colL];
      int rbase = m0 + wv * 32 + mi * 16 + g4 * 4;
      #pragma unroll
      for (int rr = 0; rr < 4; ++rr) {
        int row = rbase + rr;
        if (row >= M) continue;
        size_t idx = (size_t)(base + row) * 128 + colL;
        float xo = bf16_to_f(xh_all[idx]) + bf16_to_f(xl_all[idx]);
        float o = g * (acc[mi][ni][rr] + bi) + (1.0f - g) * xo;
        u16 hh, ll;
        split2(o, hh, ll);
        xh_all[idx] = hh;
        xl_all[idx] = ll;
      }
    }
  }
}

// ---------------- attention: pair-per-wave, 8 elems/lane, direct exp2 softmax ----------------
// Each 32-lane half handles one edge: sub 0-15 = k side (+q), sub 16-31 = v side.
__device__ __forceinline__ void attn_seg(
    const u16* __restrict__ kv, int start, int end,
    const int* __restrict__ srcs, const float q8[8], int lane, float accO[8]) {
  if (start >= end) return;
  float sum = 0.0f;
  float acc[8];
  #pragma unroll
  for (int i = 0; i < 8; ++i) acc[i] = 0.0f;
  const int half = lane >> 5;
  const int sub = lane & 31;
  const int bsrc = lane & 44;  // (lane&32)|(lane&12): k-lane of this head in this half
  #pragma unroll 2
  for (int e = start; e < end; e += 2) {
    int ee = e + half;
    bool valid = ee < end;
    int cl = valid ? ee : end - 1;
    int s = srcs[cl];
    uint4 u = *(const uint4*)&kv[(size_t)s * 256 + sub * 8];
    float r[8];
    r[0] = bf16_to_f((u16)(u.x & 0xffffu)); r[1] = bf16_to_f((u16)(u.x >> 16));
    r[2] = bf16_to_f((u16)(u.y & 0xffffu)); r[3] = bf16_to_f((u16)(u.y >> 16));
    r[4] = bf16_to_f((u16)(u.z & 0xffffu)); r[5] = bf16_to_f((u16)(u.z >> 16));
    r[6] = bf16_to_f((u16)(u.w & 0xffffu)); r[7] = bf16_to_f((u16)(u.w >> 16));
    float p = q8[0] * r[0];
    #pragma unroll
    for (int i = 1; i < 8; ++i) p = fmaf(q8[i], r[i], p);
    p += __shfl_xor(p, 1);
    p += __shfl_xor(p, 2);
    p = fminf(p, 100.0f);
    float w = valid ? exp2f(p) : 0.0f;
    float wB = __shfl(w, bsrc);
    sum += wB;
    #pragma unroll
    for (int i = 0; i < 8; ++i) acc[i] = fmaf(wB, r[i], acc[i]);
  }
  // merge the two pair-halves (same dst node)
  sum += __shfl_xor(sum, 32);
  #pragma unroll
  for (int i = 0; i < 8; ++i) acc[i] += __shfl_xor(acc[i], 32);
  float inv = 1.0f / (sum + 1e-16f);
  #pragma unroll
  for (int i = 0; i < 8; ++i) accO[i] = fmaf(acc[i], inv, accO[i]);
}

__global__ __launch_bounds__(256) void attn_all(
    const float* __restrict__ q_all, const u16* __restrict__ kvA,
    const u16* __restrict__ kvB1, const u16* __restrict__ kvB2,
    const int* __restrict__ ptr_all, const int* __restrict__ srcs_all,
    float* __restrict__ agg_all) {
  int wave = threadIdx.x >> 6, lane = threadIdx.x & 63;
  int node = blockIdx.x * 4 + wave;
  if (node >= NTOT2) return;
  int sub = lane & 31;
  float q8[8];
  #pragma unroll
  for (int i = 0; i < 8; ++i) q8[i] = 0.0f;
  if (sub < 16) {
    const float* qp = &q_all[(size_t)node * 128 + sub * 8];
    float4 a = *(const float4*)qp;
    float4 b = *(const float4*)(qp + 4);
    q8[0] = a.x * LOG2E; q8[1] = a.y * LOG2E; q8[2] = a.z * LOG2E; q8[3] = a.w * LOG2E;
    q8[4] = b.x * LOG2E; q8[5] = b.y * LOG2E; q8[6] = b.z * LOG2E; q8[7] = b.w * LOG2E;
  }
  float accO[8];
  #pragma unroll
  for (int i = 0; i < 8; ++i) accO[i] = 0.0f;
  if (node < NC) {
    attn_seg(kvA, ptr_all[node], ptr_all[node + 1], srcs_all, q8, lane, accO);
    attn_seg(kvB1, ptr_all[NC + node], ptr_all[NC + node + 1], srcs_all, q8, lane, accO);
  } else {
    int idx = 2 * NC + (node - NC);
    attn_seg(kvB2, ptr_all[idx], ptr_all[idx + 1], srcs_all, q8, lane, accO);
  }
  if (lane >= 16 && lane < 32) {
    int j = lane - 16;
    float4 o0 = {accO[0], accO[1], accO[2], accO[3]};
    float4 o1 = {accO[4], accO[5], accO[6], accO[7]};
    *(float4*)&agg_all[(size_t)node * 128 + j * 8] = o0;
    *(float4*)&agg_all[(size_t)node * 128 + j * 8 + 4] = o1;
  }
}

// ---------------- final projection ----------------
__global__ __launch_bounds__(256) void gemm_out(const u16* __restrict__ Xh,
                                                const u16* __restrict__ Xl,
                                                const float* __restrict__ W,
                                                const float* __restrict__ b,
                                                float* __restrict__ out, int M) {
  __shared__ float Ws[1024];
  __shared__ float As[32][129];
  int tid = threadIdx.x;
  int m0 = blockIdx.x * 32;
  *(float4*)&Ws[tid * 4] = *(const float4*)&W[tid * 4];
  {
    int r = tid >> 3;
    int c0 = (tid & 7) * 16;
    if (m0 + r < M) {
      const u16* hp = Xh + (size_t)(m0 + r) * 128 + c0;
      const u16* lp = Xl + (size_t)(m0 + r) * 128 + c0;
      #pragma unroll
      for (int j = 0; j < 16; ++j) As[r][c0 + j] = bf16_to_f(hp[j]) + bf16_to_f(lp[j]);
    } else {
      #pragma unroll
      for (int j = 0; j < 16; ++j) As[r][c0 + j] = 0.0f;
    }
  }
  __syncthreads();
  int r = tid >> 3, c = tid & 7;
  float sum = b[c];
  #pragma unroll 16
  for (int k = 0; k < 128; ++k) sum = fmaf(As[r][k], Ws[k * 8 + c], sum);
  if (m0 + r < M) out[(size_t)(m0 + r) * 8 + c] = sum;
}

// ---------------- host orchestration ----------------
static inline size_t align256(size_t x) { return (x + 255) & ~(size_t)255; }

extern "C" void kernel_launch(void* const* d_in, const int* in_sizes, int n_in,
                              void* d_out, int out_size, void* d_ws, size_t ws_size,
                              hipStream_t stream) {
  const float* x_context = (const float*)d_in[0];
  const float* x_question = (const float*)d_in[1];
  const int* src_q2c = (const int*)d_in[2];
  const int* dst_q2c = (const int*)d_in[3];
  const int* src_c2c = (const int*)d_in[4];
  const int* dst_c2c = (const int*)d_in[5];
  const int* src_c2q = (const int*)d_in[6];
  const int* dst_c2q = (const int*)d_in[7];
  const float* inWc = (const float*)d_in[8];
  const float* inbc = (const float*)d_in[9];
  const float* inWq = (const float*)d_in[10];
  const float* inbq = (const float*)d_in[11];
  const float* kW = (const float*)d_in[12];
  const float* kB = (const float*)d_in[13];
  const float* qW = (const float*)d_in[14];
  const float* qB = (const float*)d_in[15];
  const float* vW = (const float*)d_in[16];
  const float* vB = (const float*)d_in[17];
  const float* aW = (const float*)d_in[18];
  const float* aB = (const float*)d_in[19];
  const float* skip = (const float*)d_in[20];
  const float* arel = (const float*)d_in[21];
  const float* mrel = (const float*)d_in[22];
  const float* prel = (const float*)d_in[23];
  const float* outW = (const float*)d_in[24];
  const float* outb = (const float*)d_in[25];

  char* base = (char*)d_ws;
  size_t off = 0;
  auto carve = [&](size_t bytes) -> void* {
    void* p = base + off;
    off = align256(off + bytes);
    return p;
  };
  u16* xh_all = (u16*)carve((size_t)NTOT2 * 128 * 2);
  u16* xl_all = (u16*)carve((size_t)NTOT2 * 128 * 2);
  float* q_all = (float*)carve((size_t)NTOT2 * 128 * 4);
  u16* kvA = (u16*)carve((size_t)NQ * 256 * 2);
  u16* kvB1 = (u16*)carve((size_t)NC * 256 * 2);
  u16* kvB2 = (u16*)carve((size_t)NC * 256 * 2);
  float* agg_all = (float*)carve((size_t)NTOT2 * 128 * 4);
  u16* Bth = (u16*)carve((size_t)1280 * 128 * 2);
  u16* Btl = (u16*)carve((size_t)1280 * 128 * 2);
  float* biasBuf = (float*)carve(1280 * 4);
  int* ptr_all = (int*)carve((size_t)(NTOT + 1) * 4);
  int* srcs_all = (int*)carve((size_t)3 * NEDGE * 4);
  int* counts = (int*)carve((size_t)NTOT * 4);
  int* cursor = (int*)carve((size_t)NTOT * 4);
  int* blksums = (int*)carve(2048 * 4);

  // ---- fused CSR build ----
  {
    int nb = (NTOT + 255) / 256;
    hipMemsetAsync(counts, 0, (size_t)NTOT * 4, stream);
    k_count3<<<(3 * NEDGE + 255) / 256, 256, 0, stream>>>(dst_q2c, dst_c2c, dst_c2q, counts);
    k_scan_block<<<nb, 256, 0, stream>>>(counts, ptr_all, blksums, NTOT);
    k_scan_sums<<<1, 1024, 0, stream>>>(blksums, nb);
    k_scan_add<<<nb, 256, 0, stream>>>(ptr_all, blksums, NTOT, 3 * NEDGE);
    k_copy<<<nb, 256, 0, stream>>>(cursor, ptr_all, NTOT);
    k_scatter3<<<(3 * NEDGE + 255) / 256, 256, 0, stream>>>(
        src_q2c, src_c2c, src_c2q, dst_q2c, dst_c2c, dst_c2q, cursor, srcs_all);
  }

  // ---- merged input projections ----
  split_in<<<dim3(128, 2), 256, 0, stream>>>(inWc, inbc, inWq, inbq, Bth, Btl, biasBuf);
  in_gemm<<<NBALL, 256, 0, stream>>>(x_context, x_question, Bth, Btl, biasBuf, xh_all, xl_all);

  for (int l = 0; l < 2; ++l) {
    prep_all<<<dim3(128, 10), 128, 0, stream>>>(kW, kB, qW, qB, vW, vB, aW, aB,
                                                arel, mrel, prel, l, Bth, Btl, biasBuf);
    proj_all<<<dim3(NBALL, 5), 256, 0, stream>>>(xh_all, xl_all, Bth, Btl, biasBuf,
                                                 q_all, kvA, kvB1, kvB2);
    attn_all<<<(NTOT2 + 3) / 4, 256, 0, stream>>>(q_all, kvA, kvB1, kvB2,
                                                  ptr_all, srcs_all, agg_all);
    aproj_all<<<NBALL, 256, 0, stream>>>(agg_all, Bth, Btl, biasBuf,
                                         xh_all, xl_all, skip, l);
  }

  gemm_out<<<(NC + 31) / 32, 256, 0, stream>>>(xh_all, xl_all, outW, outb, (float*)d_out, NC);
}

// Round 8
// 790.703 us; speedup vs baseline: 1.9563x; 1.1255x over previous
//
#include <hip/hip_runtime.h>

constexpr int NC = 100000;
constexpr int NQ = 20000;
constexpr int FC = 300;
constexpr int FQ = 768;
constexpr int NEDGE = 400000;
constexpr int NTOT = NC + NC + NQ;   // concatenated dst segments: et0 | et1 | et2
constexpr int NTOT2 = NC + NQ;       // all nodes (context then question)
constexpr int NB0 = (NC + 127) / 128;  // 782
constexpr int NB1 = (NQ + 127) / 128;  // 157
constexpr int NBALL = NB0 + NB1;       // 939
constexpr int NBC64 = (NC + 63) / 64;  // 1563
constexpr int NBQ64 = (NQ + 63) / 64;  // 313
constexpr int NBALL64 = NBC64 + NBQ64; // 1876
constexpr float SCALE = 0.17677669529663687f;  // 1/sqrt(32)
constexpr float LOG2E = 1.4426950408889634f;

typedef __attribute__((ext_vector_type(8))) short bf16x8;
typedef __attribute__((ext_vector_type(4))) float f32x4;
typedef unsigned short u16;

__device__ __forceinline__ float gelu_f(float x) {
  return 0.5f * x * (1.0f + erff(x * 0.7071067811865476f));
}
__device__ __forceinline__ u16 bf16_rne(float x) {
  unsigned u = __float_as_uint(x);
  unsigned r = u + 0x7fffu + ((u >> 16) & 1u);
  return (u16)(r >> 16);
}
__device__ __forceinline__ float bf16_to_f(u16 h) {
  return __uint_as_float(((unsigned)h) << 16);
}
__device__ __forceinline__ void split2(float x, u16& hi, u16& lo) {
  hi = bf16_rne(x);
  lo = bf16_rne(x - bf16_to_f(hi));
}
// truncation split: cheaper, residual captured exactly to 2^-17 (Al*Bl term dropped anyway)
__device__ __forceinline__ void splitT(float x, u16& hi, u16& lo) {
  hi = (u16)(__float_as_uint(x) >> 16);
  lo = bf16_rne(x - bf16_to_f(hi));
}

// ---------------- fused CSR build over 3 edge types ----------------
__global__ void k_count3(const int* __restrict__ d0, const int* __restrict__ d1,
                         const int* __restrict__ d2, int* __restrict__ counts) {
  int i = blockIdx.x * 256 + threadIdx.x;
  if (i >= 3 * NEDGE) return;
  int et = i / NEDGE, e = i - et * NEDGE;
  int d = (et == 0) ? d0[e] : (et == 1) ? d1[e] : d2[e];
  int base = (et == 0) ? 0 : (et == 1) ? NC : 2 * NC;
  atomicAdd(&counts[base + d], 1);
}

__global__ void k_scan_block(const int* __restrict__ in, int* __restrict__ out,
                             int* __restrict__ bsum, int n) {
  __shared__ int s[256];
  int tid = threadIdx.x;
  int i = blockIdx.x * 256 + tid;
  int v = (i < n) ? in[i] : 0;
  s[tid] = v;
  __syncthreads();
  for (int off = 1; off < 256; off <<= 1) {
    int t = (tid >= off) ? s[tid - off] : 0;
    __syncthreads();
    s[tid] += t;
    __syncthreads();
  }
  if (i < n) out[i] = s[tid] - v;
  if (tid == 255) bsum[blockIdx.x] = s[255];
}

__global__ void k_scan_sums(int* __restrict__ bsum, int nb) {
  __shared__ int s[1024];
  int tid = threadIdx.x;
  int v = (tid < nb) ? bsum[tid] : 0;
  s[tid] = v;
  __syncthreads();
  for (int off = 1; off < 1024; off <<= 1) {
    int t = (tid >= off) ? s[tid - off] : 0;
    __syncthreads();
    s[tid] += t;
    __syncthreads();
  }
  if (tid < nb) bsum[tid] = s[tid] - v;
}

__global__ void k_scan_add(int* __restrict__ ptr, const int* __restrict__ bsum, int n, int total) {
  int i = blockIdx.x * 256 + threadIdx.x;
  if (i < n) ptr[i] += bsum[blockIdx.x];
  if (i == 0) ptr[n] = total;
}

__global__ void k_copy(int* __restrict__ dst, const int* __restrict__ src, int n) {
  int i = blockIdx.x * 256 + threadIdx.x;
  if (i < n) dst[i] = src[i];
}

__global__ void k_scatter3(const int* __restrict__ s0, const int* __restrict__ s1,
                           const int* __restrict__ s2, const int* __restrict__ d0,
                           const int* __restrict__ d1, const int* __restrict__ d2,
                           int* __restrict__ cursor, int* __restrict__ srcs_out) {
  int i = blockIdx.x * 256 + threadIdx.x;
  if (i >= 3 * NEDGE) return;
  int et = i / NEDGE, e = i - et * NEDGE;
  int d = (et == 0) ? d0[e] : (et == 1) ? d1[e] : d2[e];
  int sv = (et == 0) ? s0[e] : (et == 1) ? s1[e] : s2[e];
  int base = (et == 0) ? 0 : (et == 1) ? NC : 2 * NC;
  int p = atomicAdd(&cursor[base + d], 1);
  srcs_out[p] = sv;
}

// ---------------- per-layer B prep: 10 slabs, Kp=128 ----------------
__global__ void prep_all(const float* __restrict__ kW, const float* __restrict__ kB,
                         const float* __restrict__ qW, const float* __restrict__ qB,
                         const float* __restrict__ vW, const float* __restrict__ vB,
                         const float* __restrict__ aW, const float* __restrict__ aB,
                         const float* __restrict__ arel, const float* __restrict__ mrel,
                         const float* __restrict__ prel, int l,
                         u16* __restrict__ Bth, u16* __restrict__ Btl,
                         float* __restrict__ biasOut) {
  int i = blockIdx.x;     // input dim 0..127
  int col = threadIdx.x;  // output col 0..127
  int y = blockIdx.y;
  size_t lw = (size_t)l * 2 * 16384, lb = (size_t)l * 2 * 128;
  size_t le = (size_t)l * 3 * 4096, lp = (size_t)l * 3 * 4;
  const float *W = nullptr, *bb = nullptr, *rel = nullptr, *pr = nullptr;
  float mscale = 1.0f;
  bool fold = false;
  switch (y) {
    case 0: W = qW + lw; bb = qB + lb; break;
    case 1: fold = true; W = kW + lw; bb = kB + lb; rel = arel + le + 4096; pr = prel + lp + 4; mscale = SCALE; break;
    case 2: fold = true; W = vW + lw; bb = vB + lb; rel = mrel + le + 4096; break;
    case 3: fold = true; W = kW + lw; bb = kB + lb; rel = arel + le + 8192; pr = prel + lp + 8; mscale = SCALE; break;
    case 4: fold = true; W = vW + lw; bb = vB + lb; rel = mrel + le + 8192; break;
    case 5: W = qW + lw + 16384; bb = qB + lb + 128; break;
    case 6: fold = true; W = kW + lw + 16384; bb = kB + lb + 128; rel = arel + le; pr = prel + lp; mscale = SCALE; break;
    case 7: fold = true; W = vW + lw + 16384; bb = vB + lb + 128; rel = mrel + le; break;
    case 8: W = aW + lw; bb = aB + lb; break;
    default: W = aW + lw + 16384; bb = aB + lb + 128; break;
  }
  int colOff = y * 128;
  if (!fold) {
    float v = W[i * 128 + col];
    u16 hi, lo;
    split2(v, hi, lo);
    Bth[(size_t)(colOff + col) * 128 + i] = hi;
    Btl[(size_t)(colOff + col) * 128 + i] = lo;
    if (i == 0) biasOut[colOff + col] = bb[col];
    return;
  }
  int h = col >> 5, f = col & 31;
  float m = (pr ? pr[h] : 1.0f) * mscale;
  float s = 0.0f;
  #pragma unroll
  for (int d = 0; d < 32; ++d)
    s += W[i * 128 + h * 32 + d] * rel[(h * 32 + d) * 32 + f];
  s *= m;
  u16 hi, lo;
  split2(s, hi, lo);
  Bth[(size_t)(colOff + col) * 128 + i] = hi;
  Btl[(size_t)(colOff + col) * 128 + i] = lo;
  if (i == 0) {
    float sb = 0.0f;
    #pragma unroll
    for (int d = 0; d < 32; ++d)
      sb += bb[h * 32 + d] * rel[(h * 32 + d) * 32 + f];
    biasOut[colOff + col] = sb * m;
  }
}

// ---------------- input weight split: y=0 context (K=300,Kp=320), y=1 question (768,768) ----
__global__ void split_in(const float* __restrict__ Wc, const float* __restrict__ bc,
                         const float* __restrict__ Wq, const float* __restrict__ bq,
                         u16* __restrict__ Bth, u16* __restrict__ Btl,
                         float* __restrict__ biasOut) {
  int n = blockIdx.x, y = blockIdx.y;
  const float* W = y ? Wq : Wc;
  const float* b = y ? bq : bc;
  int K = y ? FQ : FC, Kp = y ? 768 : 320;
  size_t boff = y ? (size_t)128 * 320 : 0;
  for (int k = threadIdx.x; k < Kp; k += 256) {
    float v = (k < K) ? W[(size_t)k * 128 + n] : 0.0f;
    u16 hi, lo;
    split2(v, hi, lo);
    Bth[boff + (size_t)n * Kp + k] = hi;
    Btl[boff + (size_t)n * Kp + k] = lo;
  }
  if (threadIdx.x == 0) biasOut[(y ? 128 : 0) + n] = b[n];
}

// ---------------- pipelined f32-A GEMM, BM=64, 3-term split, prefetch-next-tile -------------
// MODE 1: input projections (relu; A routed context/question; writes x split pair)
// MODE 2: a-projection (gelu on A=agg; skip-gate epilogue; updates x split pair)
template <int MODE>
__global__ __launch_bounds__(256) void pipe_gemm(
    const float* __restrict__ Ac, const float* __restrict__ Aq,
    const u16* __restrict__ Bth, const u16* __restrict__ Btl,
    const float* __restrict__ biasBuf,
    u16* __restrict__ xh_all, u16* __restrict__ xl_all,
    const float* __restrict__ skip, int l) {
  __shared__ u16 Ah[64][40], Al[64][40];
  __shared__ u16 Bh[128][40], Bl[128][40];
  const int tid = threadIdx.x, lane = tid & 63, wv = tid >> 6;
  const int l15 = lane & 15, g4 = lane >> 4, koff = g4 * 8;
  const int srA = tid >> 2, scA = (tid & 3) * 8;   // A: 8 f32/thread
  const int srB = tid >> 1, scB = (tid & 1) * 16;  // B: 16 u16/thread/array

  const int bid = blockIdx.x;
  const int nt = (bid < NBC64) ? 0 : 1;
  const int m0 = nt ? (bid - NBC64) * 64 : bid * 64;
  const int M = nt ? NQ : NC;
  const int rowbase = nt ? NC : 0;
  const float* A32;
  int K, Kp, biasOff;
  size_t boff, arow;
  if (MODE == 1) {
    if (nt == 0) { A32 = Ac; K = FC; Kp = 320; boff = 0; biasOff = 0; }
    else { A32 = Aq; K = FQ; Kp = 768; boff = (size_t)128 * 320; biasOff = 128; }
    arow = (size_t)(m0 + srA) * K;
  } else {
    A32 = Ac;
    K = 128; Kp = 128;
    boff = (size_t)(8 + nt) * 128 * 128;
    biasOff = (8 + nt) * 128;
    arow = (size_t)(rowbase + m0 + srA) * 128;
  }
  const bool rowokA = (m0 + srA) < M;
  const int nk = (K + 31) / 32;

  f32x4 acc[8];
  #pragma unroll
  for (int ni = 0; ni < 8; ++ni) acc[ni] = (f32x4){0.f, 0.f, 0.f, 0.f};

  auto loadA = [&](float va[8], int k0) {
    if (rowokA && (k0 + 32 <= K)) {
      const float* ap = A32 + arow + k0 + scA;
      float4 f0 = *(const float4*)ap;
      float4 f1 = *(const float4*)(ap + 4);
      va[0] = f0.x; va[1] = f0.y; va[2] = f0.z; va[3] = f0.w;
      va[4] = f1.x; va[5] = f1.y; va[6] = f1.z; va[7] = f1.w;
    } else {
      #pragma unroll
      for (int j = 0; j < 8; ++j) {
        int kc = k0 + scA + j;
        va[j] = (rowokA && kc < K) ? A32[arow + kc] : 0.0f;
      }
    }
  };
  auto loadB = [&](uint4& bh0, uint4& bh1, uint4& bl0, uint4& bl1, int k0) {
    const u16* bp = Bth + boff + (size_t)srB * Kp + k0 + scB;
    bh0 = *(const uint4*)bp;
    bh1 = *(const uint4*)(bp + 8);
    const u16* lp = Btl + boff + (size_t)srB * Kp + k0 + scB;
    bl0 = *(const uint4*)lp;
    bl1 = *(const uint4*)(lp + 8);
  };

  float vaC[8];
  uint4 bhC0, bhC1, blC0, blC1;
  loadA(vaC, 0);
  loadB(bhC0, bhC1, blC0, blC1, 0);

  for (int ks = 0; ks < nk; ++ks) {
    // ---- stage current tile to LDS (split A here) ----
    {
      alignas(16) u16 hv[8], lv[8];
      #pragma unroll
      for (int j = 0; j < 8; ++j) {
        float x = (MODE == 2) ? gelu_f(vaC[j]) : vaC[j];
        splitT(x, hv[j], lv[j]);
      }
      *(uint4*)&Ah[srA][scA] = *(const uint4*)&hv[0];
      *(uint4*)&Al[srA][scA] = *(const uint4*)&lv[0];
      *(uint4*)&Bh[srB][scB] = bhC0;
      *(uint4*)&Bh[srB][scB + 8] = bhC1;
      *(uint4*)&Bl[srB][scB] = blC0;
      *(uint4*)&Bl[srB][scB + 8] = blC1;
    }
    __syncthreads();

    // ---- issue next tile's global loads (overlap with MFMA below) ----
    float vaN[8];
    uint4 bhN0, bhN1, blN0, blN1;
    const bool more = (ks + 1) < nk;
    if (more) {
      loadA(vaN, (ks + 1) * 32);
      loadB(bhN0, bhN1, blN0, blN1, (ks + 1) * 32);
    }

    // ---- MFMA on current tile ----
    {
      int row = wv * 16 + l15;
      bf16x8 a_h = *(const bf16x8*)&Ah[row][koff];
      bf16x8 a_l = *(const bf16x8*)&Al[row][koff];
      #pragma unroll
      for (int ni = 0; ni < 8; ++ni) {
        int col = ni * 16 + l15;
        bf16x8 b_h = *(const bf16x8*)&Bh[col][koff];
        bf16x8 b_l = *(const bf16x8*)&Bl[col][koff];
        acc[ni] = __builtin_amdgcn_mfma_f32_16x16x32_bf16(a_h, b_h, acc[ni], 0, 0, 0);
        acc[ni] = __builtin_amdgcn_mfma_f32_16x16x32_bf16(a_l, b_h, acc[ni], 0, 0, 0);
        acc[ni] = __builtin_amdgcn_mfma_f32_16x16x32_bf16(a_h, b_l, acc[ni], 0, 0, 0);
      }
    }
    __syncthreads();

    if (more) {
      #pragma unroll
      for (int j = 0; j < 8; ++j) vaC[j] = vaN[j];
      bhC0 = bhN0; bhC1 = bhN1; blC0 = blN0; blC1 = blN1;
    }
  }

  float g = 1.0f;
  if (MODE == 2) g = 1.0f / (1.0f + __expf(-skip[l * 2 + nt]));

  #pragma unroll
  for (int ni = 0; ni < 8; ++ni) {
    int colL = ni * 16 + l15;
    float bi = biasBuf[biasOff + colL];
    int rbase = m0 + wv * 16 + g4 * 4;
    #pragma unroll
    for (int rr = 0; rr < 4; ++rr) {
      int row = rbase + rr;
      if (row >= M) continue;
      size_t idx = (size_t)(rowbase + row) * 128 + colL;
      float o = acc[ni][rr] + bi;
      if (MODE == 1) {
        o = fmaxf(o, 0.0f);
      } else {
        float xo = bf16_to_f(xh_all[idx]) + bf16_to_f(xl_all[idx]);
        o = g * o + (1.0f - g) * xo;
      }
      u16 hh, ll;
      split2(o, hh, ll);
      xh_all[idx] = hh;
      xl_all[idx] = ll;
    }
  }
}

// ---------------- merged q/kv projection GEMM: 1-term bf16 (xh @ Bh), slab-routed C ----------
__global__ __launch_bounds__(256) void proj_all(
    const u16* __restrict__ xh_all, const u16* __restrict__ xl_all,
    const u16* __restrict__ Bth, const u16* __restrict__ Btl,
    const float* __restrict__ biasBuf,
    u16* __restrict__ q_all, u16* __restrict__ kvA,
    u16* __restrict__ kvB1, u16* __restrict__ kvB2) {
  int bid = blockIdx.x, y = blockIdx.y;
  int nt = (bid < NB0) ? 0 : 1;
  if (nt == 1 && y >= 3) return;
  __shared__ u16 Ah[128][40];
  __shared__ u16 Bh[128][40];
  int m0 = nt ? (bid - NB0) * 128 : bid * 128;
  int M = nt ? NQ : NC;
  int abase = nt ? NC : 0;
  int bslab = nt ? 5 + y : y;
  u16* cp; int ld, cb, crowbase;
  if (nt == 0) {
    switch (y) {
      case 0: cp = q_all; ld = 128; cb = 0; crowbase = 0; break;
      case 1: cp = kvB1; ld = 256; cb = 0; crowbase = 0; break;
      case 2: cp = kvB1; ld = 256; cb = 128; crowbase = 0; break;
      case 3: cp = kvB2; ld = 256; cb = 0; crowbase = 0; break;
      default: cp = kvB2; ld = 256; cb = 128; crowbase = 0; break;
    }
  } else {
    switch (y) {
      case 0: cp = q_all; ld = 128; cb = 0; crowbase = NC; break;
      case 1: cp = kvA; ld = 256; cb = 0; crowbase = 0; break;
      default: cp = kvA; ld = 256; cb = 128; crowbase = 0; break;
    }
  }
  const int tid = threadIdx.x, lane = tid & 63, wv = tid >> 6;
  const int l15 = lane & 15, g4 = lane >> 4, koff = g4 * 8;
  const int sr = tid >> 1, sc = (tid & 1) * 16;
  const bool rowok = (m0 + sr) < M;

  f32x4 acc[2][8];
  #pragma unroll
  for (int mi = 0; mi < 2; ++mi)
    #pragma unroll
    for (int ni = 0; ni < 8; ++ni) acc[mi][ni] = (f32x4){0.f, 0.f, 0.f, 0.f};

  for (int k0 = 0; k0 < 128; k0 += 32) {
    uint4 h0 = {0, 0, 0, 0}, h1 = {0, 0, 0, 0};
    if (rowok) {
      const u16* ap = xh_all + (size_t)(abase + m0 + sr) * 128 + k0 + sc;
      h0 = *(const uint4*)ap;
      h1 = *(const uint4*)(ap + 8);
    }
    *(uint4*)&Ah[sr][sc] = h0;
    *(uint4*)&Ah[sr][sc + 8] = h1;
    {
      const u16* bp = Bth + (size_t)(bslab * 128 + sr) * 128 + k0 + sc;
      *(uint4*)&Bh[sr][sc] = *(const uint4*)bp;
      *(uint4*)&Bh[sr][sc + 8] = *(const uint4*)(bp + 8);
    }
    __syncthreads();

    bf16x8 a_h[2];
    #pragma unroll
    for (int mi = 0; mi < 2; ++mi) {
      int row = wv * 32 + mi * 16 + l15;
      a_h[mi] = *(const bf16x8*)&Ah[row][koff];
    }
    #pragma unroll
    for (int ni = 0; ni < 8; ++ni) {
      int col = ni * 16 + l15;
      bf16x8 b_h = *(const bf16x8*)&Bh[col][koff];
      #pragma unroll
      for (int mi = 0; mi < 2; ++mi)
        acc[mi][ni] = __builtin_amdgcn_mfma_f32_16x16x32_bf16(a_h[mi], b_h, acc[mi][ni], 0, 0, 0);
    }
    __syncthreads();
  }

  #pragma unroll
  for (int mi = 0; mi < 2; ++mi) {
    #pragma unroll
    for (int ni = 0; ni < 8; ++ni) {
      int colL = ni * 16 + l15;
      float bi = biasBuf[bslab * 128 + colL];
      int rbase = m0 + wv * 32 + mi * 16 + g4 * 4;
      #pragma unroll
      for (int rr = 0; rr < 4; ++rr) {
        int row = rbase + rr;
        if (row >= M) continue;
        float o = acc[mi][ni][rr] + bi;
        cp[(size_t)(crowbase + row) * ld + cb + colL] = bf16_rne(o);
      }
    }
  }
}

// ---------------- attention: pair-per-wave, 8 elems/lane, direct exp2 softmax ----------------
__device__ __forceinline__ void attn_seg(
    const u16* __restrict__ kv, int start, int end,
    const int* __restrict__ srcs, const float q8[8], int lane, float accO[8]) {
  if (start >= end) return;
  float sum = 0.0f;
  float acc[8];
  #pragma unroll
  for (int i = 0; i < 8; ++i) acc[i] = 0.0f;
  const int half = lane >> 5;
  const int sub = lane & 31;
  const int bsrc = lane & 44;  // k-lane of this head in this half
  #pragma unroll 2
  for (int e = start; e < end; e += 2) {
    int ee = e + half;
    bool valid = ee < end;
    int cl = valid ? ee : end - 1;
    int s = srcs[cl];
    uint4 u = *(const uint4*)&kv[(size_t)s * 256 + sub * 8];
    float r[8];
    r[0] = bf16_to_f((u16)(u.x & 0xffffu)); r[1] = bf16_to_f((u16)(u.x >> 16));
    r[2] = bf16_to_f((u16)(u.y & 0xffffu)); r[3] = bf16_to_f((u16)(u.y >> 16));
    r[4] = bf16_to_f((u16)(u.z & 0xffffu)); r[5] = bf16_to_f((u16)(u.z >> 16));
    r[6] = bf16_to_f((u16)(u.w & 0xffffu)); r[7] = bf16_to_f((u16)(u.w >> 16));
    float p = q8[0] * r[0];
    #pragma unroll
    for (int i = 1; i < 8; ++i) p = fmaf(q8[i], r[i], p);
    p += __shfl_xor(p, 1);
    p += __shfl_xor(p, 2);
    p = fminf(p, 100.0f);
    float w = valid ? exp2f(p) : 0.0f;
    float wB = __shfl(w, bsrc);
    sum += wB;
    #pragma unroll
    for (int i = 0; i < 8; ++i) acc[i] = fmaf(wB, r[i], acc[i]);
  }
  sum += __shfl_xor(sum, 32);
  #pragma unroll
  for (int i = 0; i < 8; ++i) acc[i] += __shfl_xor(acc[i], 32);
  float inv = 1.0f / (sum + 1e-16f);
  #pragma unroll
  for (int i = 0; i < 8; ++i) accO[i] = fmaf(acc[i], inv, accO[i]);
}

__global__ __launch_bounds__(256) void attn_all(
    const u16* __restrict__ q_all, const u16* __restrict__ kvA,
    const u16* __restrict__ kvB1, const u16* __restrict__ kvB2,
    const int* __restrict__ ptr_all, const int* __restrict__ srcs_all,
    float* __restrict__ agg_all) {
  int wave = threadIdx.x >> 6, lane = threadIdx.x & 63;
  int node = blockIdx.x * 4 + wave;
  if (node >= NTOT2) return;
  int sub = lane & 31;
  float q8[8];
  #pragma unroll
  for (int i = 0; i < 8; ++i) q8[i] = 0.0f;
  if (sub < 16) {
    uint4 u = *(const uint4*)&q_all[(size_t)node * 128 + sub * 8];
    q8[0] = bf16_to_f((u16)(u.x & 0xffffu)) * LOG2E; q8[1] = bf16_to_f((u16)(u.x >> 16)) * LOG2E;
    q8[2] = bf16_to_f((u16)(u.y & 0xffffu)) * LOG2E; q8[3] = bf16_to_f((u16)(u.y >> 16)) * LOG2E;
    q8[4] = bf16_to_f((u16)(u.z & 0xffffu)) * LOG2E; q8[5] = bf16_to_f((u16)(u.z >> 16)) * LOG2E;
    q8[6] = bf16_to_f((u16)(u.w & 0xffffu)) * LOG2E; q8[7] = bf16_to_f((u16)(u.w >> 16)) * LOG2E;
  }
  float accO[8];
  #pragma unroll
  for (int i = 0; i < 8; ++i) accO[i] = 0.0f;
  if (node < NC) {
    attn_seg(kvA, ptr_all[node], ptr_all[node + 1], srcs_all, q8, lane, accO);
    attn_seg(kvB1, ptr_all[NC + node], ptr_all[NC + node + 1], srcs_all, q8, lane, accO);
  } else {
    int idx = 2 * NC + (node - NC);
    attn_seg(kvB2, ptr_all[idx], ptr_all[idx + 1], srcs_all, q8, lane, accO);
  }
  if (lane >= 16 && lane < 32) {
    int j = lane - 16;
    float4 o0 = {accO[0], accO[1], accO[2], accO[3]};
    float4 o1 = {accO[4], accO[5], accO[6], accO[7]};
    *(float4*)&agg_all[(size_t)node * 128 + j * 8] = o0;
    *(float4*)&agg_all[(size_t)node * 128 + j * 8 + 4] = o1;
  }
}

// ---------------- final projection ----------------
__global__ __launch_bounds__(256) void gemm_out(const u16* __restrict__ Xh,
                                                const u16* __restrict__ Xl,
                                                const float* __restrict__ W,
                                                const float* __restrict__ b,
                                                float* __restrict__ out, int M) {
  __shared__ float Ws[1024];
  __shared__ float As[32][129];
  int tid = threadIdx.x;
  int m0 = blockIdx.x * 32;
  *(float4*)&Ws[tid * 4] = *(const float4*)&W[tid * 4];
  {
    int r = tid >> 3;
    int c0 = (tid & 7) * 16;
    if (m0 + r < M) {
      const u16* hp = Xh + (size_t)(m0 + r) * 128 + c0;
      const u16* lp = Xl + (size_t)(m0 + r) * 128 + c0;
      #pragma unroll
      for (int j = 0; j < 16; ++j) As[r][c0 + j] = bf16_to_f(hp[j]) + bf16_to_f(lp[j]);
    } else {
      #pragma unroll
      for (int j = 0; j < 16; ++j) As[r][c0 + j] = 0.0f;
    }
  }
  __syncthreads();
  int r = tid >> 3, c = tid & 7;
  float sum = b[c];
  #pragma unroll 16
  for (int k = 0; k < 128; ++k) sum = fmaf(As[r][k], Ws[k * 8 + c], sum);
  if (m0 + r < M) out[(size_t)(m0 + r) * 8 + c] = sum;
}

// ---------------- host orchestration ----------------
static inline size_t align256(size_t x) { return (x + 255) & ~(size_t)255; }

extern "C" void kernel_launch(void* const* d_in, const int* in_sizes, int n_in,
                              void* d_out, int out_size, void* d_ws, size_t ws_size,
                              hipStream_t stream) {
  const float* x_context = (const float*)d_in[0];
  const float* x_question = (const float*)d_in[1];
  const int* src_q2c = (const int*)d_in[2];
  const int* dst_q2c = (const int*)d_in[3];
  const int* src_c2c = (const int*)d_in[4];
  const int* dst_c2c = (const int*)d_in[5];
  const int* src_c2q = (const int*)d_in[6];
  const int* dst_c2q = (const int*)d_in[7];
  const float* inWc = (const float*)d_in[8];
  const float* inbc = (const float*)d_in[9];
  const float* inWq = (const float*)d_in[10];
  const float* inbq = (const float*)d_in[11];
  const float* kW = (const float*)d_in[12];
  const float* kB = (const float*)d_in[13];
  const float* qW = (const float*)d_in[14];
  const float* qB = (const float*)d_in[15];
  const float* vW = (const float*)d_in[16];
  const float* vB = (const float*)d_in[17];
  const float* aW = (const float*)d_in[18];
  const float* aB = (const float*)d_in[19];
  const float* skip = (const float*)d_in[20];
  const float* arel = (const float*)d_in[21];
  const float* mrel = (const float*)d_in[22];
  const float* prel = (const float*)d_in[23];
  const float* outW = (const float*)d_in[24];
  const float* outb = (const float*)d_in[25];

  char* base = (char*)d_ws;
  size_t off = 0;
  auto carve = [&](size_t bytes) -> void* {
    void* p = base + off;
    off = align256(off + bytes);
    return p;
  };
  u16* xh_all = (u16*)carve((size_t)NTOT2 * 128 * 2);
  u16* xl_all = (u16*)carve((size_t)NTOT2 * 128 * 2);
  u16* q_all = (u16*)carve((size_t)NTOT2 * 128 * 2);
  u16* kvA = (u16*)carve((size_t)NQ * 256 * 2);
  u16* kvB1 = (u16*)carve((size_t)NC * 256 * 2);
  u16* kvB2 = (u16*)carve((size_t)NC * 256 * 2);
  float* agg_all = (float*)carve((size_t)NTOT2 * 128 * 4);
  u16* Bth = (u16*)carve((size_t)1280 * 128 * 2);
  u16* Btl = (u16*)carve((size_t)1280 * 128 * 2);
  float* biasBuf = (float*)carve(1280 * 4);
  int* ptr_all = (int*)carve((size_t)(NTOT + 1) * 4);
  int* srcs_all = (int*)carve((size_t)3 * NEDGE * 4);
  int* counts = (int*)carve((size_t)NTOT * 4);
  int* cursor = (int*)carve((size_t)NTOT * 4);
  int* blksums = (int*)carve(2048 * 4);

  // ---- fused CSR build ----
  {
    int nb = (NTOT + 255) / 256;
    hipMemsetAsync(counts, 0, (size_t)NTOT * 4, stream);
    k_count3<<<(3 * NEDGE + 255) / 256, 256, 0, stream>>>(dst_q2c, dst_c2c, dst_c2q, counts);
    k_scan_block<<<nb, 256, 0, stream>>>(counts, ptr_all, blksums, NTOT);
    k_scan_sums<<<1, 1024, 0, stream>>>(blksums, nb);
    k_scan_add<<<nb, 256, 0, stream>>>(ptr_all, blksums, NTOT, 3 * NEDGE);
    k_copy<<<nb, 256, 0, stream>>>(cursor, ptr_all, NTOT);
    k_scatter3<<<(3 * NEDGE + 255) / 256, 256, 0, stream>>>(
        src_q2c, src_c2c, src_c2q, dst_q2c, dst_c2c, dst_c2q, cursor, srcs_all);
  }

  // ---- merged input projections (pipelined) ----
  split_in<<<dim3(128, 2), 256, 0, stream>>>(inWc, inbc, inWq, inbq, Bth, Btl, biasBuf);
  pipe_gemm<1><<<NBALL64, 256, 0, stream>>>(x_context, x_question, Bth, Btl, biasBuf,
                                            xh_all, xl_all, nullptr, 0);

  for (int l = 0; l < 2; ++l) {
    prep_all<<<dim3(128, 10), 128, 0, stream>>>(kW, kB, qW, qB, vW, vB, aW, aB,
                                                arel, mrel, prel, l, Bth, Btl, biasBuf);
    proj_all<<<dim3(NBALL, 5), 256, 0, stream>>>(xh_all, xl_all, Bth, Btl, biasBuf,
                                                 q_all, kvA, kvB1, kvB2);
    attn_all<<<(NTOT2 + 3) / 4, 256, 0, stream>>>(q_all, kvA, kvB1, kvB2,
                                                  ptr_all, srcs_all, agg_all);
    pipe_gemm<2><<<NBALL64, 256, 0, stream>>>(agg_all, nullptr, Bth, Btl, biasBuf,
                                              xh_all, xl_all, skip, l);
  }

  gemm_out<<<(NC + 31) / 32, 256, 0, stream>>>(xh_all, xl_all, outW, outb, (float*)d_out, NC);
}